// Round 8
// baseline (224.012 us; speedup 1.0000x reference)
//
#include <hip/hip_runtime.h>
#include <hip/hip_bf16.h>
#include <math.h>

#define EPSF 1e-8f

typedef __attribute__((ext_vector_type(8))) short bf16x8;
typedef __attribute__((ext_vector_type(4))) float f32x4;

static __device__ __forceinline__ unsigned short f2bf(float f) {
    __hip_bfloat16 h = __float2bfloat16(f);
    return *reinterpret_cast<unsigned short*>(&h);
}
static __device__ __forceinline__ float bf2f(unsigned short u) {
    __hip_bfloat16 h;
    *reinterpret_cast<unsigned short*>(&h) = u;
    return __bfloat162float(h);
}

// async global->LDS, 16B/lane. Chunked layout: 1KB chunk = 16 rows x 32 bf16;
// lane l covers row l>>2, cols (l&3)*8..+8. Frag ds_read_b128 of a chunk hits
// each bank exactly 8x (the b128 minimum) -> conflict-free.
static __device__ __forceinline__ void async16(void* lds, const void* g) {
    __builtin_amdgcn_global_load_lds(
        (const __attribute__((address_space(1))) unsigned int*)g,
        (__attribute__((address_space(3))) unsigned int*)lds, 16, 0, 0);
}

// ---------------------------------------------------------------------------
// Combined hi/lo bf16 split of [subx; x] -> planes [31024,256].
// Zeroes gl/gy and nrm (nrm is atomically accumulated by gemm_l2).
// ---------------------------------------------------------------------------
__global__ __launch_bounds__(256) void split_combined(
    const float* __restrict__ subx, const float* __restrict__ x,
    unsigned short* __restrict__ H, unsigned short* __restrict__ L,
    float* __restrict__ gl, float* __restrict__ gy, float* __restrict__ nrm,
    int n4, int nsubrow, int nrm4)
{
    int i = blockIdx.x * 256 + threadIdx.x;
    float4 z = make_float4(0.f, 0.f, 0.f, 0.f);
    if (i < 512) {
        if (i < 256) ((float4*)gl)[i] = z;
        else         ((float4*)gy)[i - 256] = z;
    }
    if (i < nrm4) ((float4*)nrm)[i] = z;
    if (i >= n4) return;
    int row = i >> 6;   // 64 float4 per 256-col row
    float4 v = (row < nsubrow)
        ? ((const float4*)subx)[i]
        : ((const float4*)x)[i - (size_t)nsubrow * 64];
    unsigned short h0 = f2bf(v.x), h1 = f2bf(v.y), h2 = f2bf(v.z), h3 = f2bf(v.w);
    unsigned short l0 = f2bf(v.x - bf2f(h0));
    unsigned short l1 = f2bf(v.y - bf2f(h1));
    unsigned short l2 = f2bf(v.z - bf2f(h2));
    unsigned short l3 = f2bf(v.w - bf2f(h3));
    uint2 hp, lp;
    hp.x = ((unsigned)h1 << 16) | h0;  hp.y = ((unsigned)h3 << 16) | h2;
    lp.x = ((unsigned)l1 << 16) | l0;  lp.y = ((unsigned)l3 << 16) | l2;
    ((uint2*)H)[i] = hp;
    ((uint2*)L)[i] = lp;
}

// ---------------------------------------------------------------------------
// W [K,N] fp32 -> W^T hi/lo bf16 [N,K].
// ---------------------------------------------------------------------------
__global__ __launch_bounds__(256) void tsplit(
    const float* __restrict__ W, unsigned short* __restrict__ HT,
    unsigned short* __restrict__ LT, int kshift, int N, int total)
{
    int idx = blockIdx.x * 256 + threadIdx.x;
    if (idx >= total) return;
    int K = 1 << kshift;
    int n = idx >> kshift, k = idx & (K - 1);
    float w = W[(size_t)k * N + n];
    unsigned short h = f2bf(w);
    HT[idx] = h;
    LT[idx] = f2bf(w - bf2f(h));
}

// ---------------------------------------------------------------------------
// Layer-1: C = relu((Ah+Al)@(Bh+Bl)^T + bias), 3-term split-bf16 MFMA.
// STAGE-ONCE / BARRIER-FREE K-loop: the whole 64-col B-tile (hi+lo, K=256,
// 64KB) is staged into LDS once; the fully-unrolled 8-iter K-loop has NO
// barriers -- A-frags direct from global, B-frags ds_read, compiler
// schedules with fine-grained vmcnt/lgkmcnt, waves slip freely.
// 3 barriers per block total (stage / pre-ctile / pre-store).
// LDS 64KB -> 2 blocks/CU: if this is faster at LOWER occupancy than R7,
// the lock-step-barrier theory is confirmed.
// ---------------------------------------------------------------------------
__global__ __launch_bounds__(256, 2) void gemm_l1(
    const unsigned short* __restrict__ Ah, const unsigned short* __restrict__ Al,
    const unsigned short* __restrict__ BhT, const unsigned short* __restrict__ BlT,
    const float* __restrict__ bias, unsigned short* __restrict__ Cout, int M)
{
    const int K = 256, N = 512;
    // 64 chunks of 1KB: chunk(plane, nc, kc) at (plane*32 + nc*8 + kc)*512
    __shared__ __align__(16) unsigned short sB[32768];

    // XCD swizzle: contiguous newbid range per XCD (m-slice + full B in L2)
    const int nb = gridDim.x;
    const int per = nb >> 3, rem = nb & 7;
    const int xcd = blockIdx.x & 7, slot = blockIdx.x >> 3;
    const int newbid = xcd * per + min(xcd, rem) + slot;
    const int m0 = (newbid >> 3) * 128, n0 = (newbid & 7) * 64;

    const int t = threadIdx.x, wave = t >> 6, lane = t & 63;
    const int quad = lane >> 4, lq = lane & 15;
    const int rsub = lane >> 2, kc8 = (lane & 3) * 8;

    // stage the whole B tile once: 64 chunks, 16 per wave
    #pragma unroll
    for (int q = 0; q < 16; ++q) {
        int c = wave * 16 + q;
        int plane = c >> 5, idx = c & 31, nc = idx >> 3, kc = idx & 7;
        const unsigned short* src = (plane ? BlT : BhT)
            + (size_t)(n0 + nc * 16 + rsub) * K + kc * 32 + kc8;
        async16(sB + c * 512, src);
    }

    // A fragment row bases (direct global frags), rows wave*32 + mi*16
    const unsigned short* pAh[2];
    const unsigned short* pAl[2];
    #pragma unroll
    for (int mi = 0; mi < 2; ++mi) {
        size_t r = (size_t)min(m0 + wave * 32 + mi * 16 + lq, M - 1) * K + quad * 8;
        pAh[mi] = Ah + r;
        pAl[mi] = Al + r;
    }

    f32x4 acc[2][4];
    #pragma unroll
    for (int i = 0; i < 2; ++i)
        #pragma unroll
        for (int j = 0; j < 4; ++j) acc[i][j] = (f32x4){0.f, 0.f, 0.f, 0.f};

    __syncthreads();   // B staged (compiler drains vmcnt here, once)

    #pragma unroll
    for (int kc = 0; kc < 8; ++kc) {
        const int k0 = kc * 32;
        bf16x8 fAh[2], fAl[2];
        #pragma unroll
        for (int mi = 0; mi < 2; ++mi) {
            fAh[mi] = *(const bf16x8*)(pAh[mi] + k0);
            fAl[mi] = *(const bf16x8*)(pAl[mi] + k0);
        }
        #pragma unroll
        for (int ni = 0; ni < 4; ++ni) {
            int off = (ni * 8 + kc) * 512 + lq * 32 + quad * 8;
            bf16x8 fBh = *(const bf16x8*)&sB[off];
            bf16x8 fBl = *(const bf16x8*)&sB[16384 + off];
            #pragma unroll
            for (int mi = 0; mi < 2; ++mi) {
                f32x4 a = acc[mi][ni];
                a = __builtin_amdgcn_mfma_f32_16x16x32_bf16(fAh[mi], fBh, a, 0, 0, 0);
                a = __builtin_amdgcn_mfma_f32_16x16x32_bf16(fAh[mi], fBl, a, 0, 0, 0);
                a = __builtin_amdgcn_mfma_f32_16x16x32_bf16(fAl[mi], fBh, a, 0, 0, 0);
                acc[mi][ni] = a;
            }
        }
    }

    // epilogue: 2 passes of 64 rows through a 64x72 ctile (aliases sB)
    unsigned short* ctile = sB;
    float bv[4];
    #pragma unroll
    for (int ni = 0; ni < 4; ++ni) bv[ni] = bias[n0 + ni * 16 + lq];
    #pragma unroll
    for (int p = 0; p < 2; ++p) {
        __syncthreads();
        if ((wave >> 1) == p) {
            int lrow0 = (wave & 1) * 32;
            #pragma unroll
            for (int mi = 0; mi < 2; ++mi)
                #pragma unroll
                for (int ni = 0; ni < 4; ++ni)
                    #pragma unroll
                    for (int r = 0; r < 4; ++r) {
                        float v = fmaxf(acc[mi][ni][r] + bv[ni], 0.f);
                        ctile[(lrow0 + mi * 16 + quad * 4 + r) * 72 + ni * 16 + lq] = f2bf(v);
                    }
        }
        __syncthreads();
        #pragma unroll
        for (int it = 0; it < 2; ++it) {
            int flat = it * 256 + t;
            int row = flat >> 3, seg = flat & 7;
            int gm = m0 + p * 64 + row;
            if (gm < M) {
                bf16x8 v = *(const bf16x8*)&ctile[row * 72 + seg * 8];
                *(bf16x8*)&Cout[(size_t)gm * N + n0 + seg * 8] = v;
            }
        }
    }
}

// ---------------------------------------------------------------------------
// Layer-2: C = relu(A@(Bh+Bl)^T + bias), 2-term split on weights.
// Same stage-once barrier-free structure. 128x32 tile; W2^T tile
// (32 cols x K=512 x hi+lo = 64KB) staged once; 16 unrolled k-iters with
// A (z1) frags direct from global. Row-norm partials atomicAdd'ed into nrm.
// ---------------------------------------------------------------------------
__global__ __launch_bounds__(256, 2) void gemm_l2_norm(
    const unsigned short* __restrict__ A,
    const unsigned short* __restrict__ BhT, const unsigned short* __restrict__ BlT,
    const float* __restrict__ bias, unsigned short* __restrict__ Cout,
    float* __restrict__ nrm, int M)
{
    const int K = 512, N = 128;
    // 64 chunks: chunk(plane, nc, kc) at (plane*32 + nc*16 + kc)*512
    __shared__ __align__(16) unsigned short sB[32768];

    const int nb = gridDim.x;
    const int per = nb >> 3, rem = nb & 7;
    const int xcd = blockIdx.x & 7, slot = blockIdx.x >> 3;
    const int newbid = xcd * per + min(xcd, rem) + slot;
    const int m0 = (newbid >> 2) * 128, n0 = (newbid & 3) * 32;

    const int t = threadIdx.x, wave = t >> 6, lane = t & 63;
    const int quad = lane >> 4, lq = lane & 15;
    const int rsub = lane >> 2, kc8 = (lane & 3) * 8;

    #pragma unroll
    for (int q = 0; q < 16; ++q) {
        int c = wave * 16 + q;
        int plane = c >> 5, idx = c & 31, nc = idx >> 4, kc = idx & 15;
        const unsigned short* src = (plane ? BlT : BhT)
            + (size_t)(n0 + nc * 16 + rsub) * K + kc * 32 + kc8;
        async16(sB + c * 512, src);
    }

    const unsigned short* pA[2];
    #pragma unroll
    for (int mi = 0; mi < 2; ++mi)
        pA[mi] = A + (size_t)min(m0 + wave * 32 + mi * 16 + lq, M - 1) * K + quad * 8;

    f32x4 acc[2][2];
    #pragma unroll
    for (int i = 0; i < 2; ++i)
        #pragma unroll
        for (int j = 0; j < 2; ++j) acc[i][j] = (f32x4){0.f, 0.f, 0.f, 0.f};

    __syncthreads();

    #pragma unroll
    for (int kc = 0; kc < 16; ++kc) {
        const int k0 = kc * 32;
        bf16x8 fA[2];
        #pragma unroll
        for (int mi = 0; mi < 2; ++mi) fA[mi] = *(const bf16x8*)(pA[mi] + k0);
        #pragma unroll
        for (int ni = 0; ni < 2; ++ni) {
            int off = (ni * 16 + kc) * 512 + lq * 32 + quad * 8;
            bf16x8 fBh = *(const bf16x8*)&sB[off];
            bf16x8 fBl = *(const bf16x8*)&sB[16384 + off];
            #pragma unroll
            for (int mi = 0; mi < 2; ++mi) {
                f32x4 a = acc[mi][ni];
                a = __builtin_amdgcn_mfma_f32_16x16x32_bf16(fA[mi], fBh, a, 0, 0, 0);
                a = __builtin_amdgcn_mfma_f32_16x16x32_bf16(fA[mi], fBl, a, 0, 0, 0);
                acc[mi][ni] = a;
            }
        }
    }

    // epilogue: ctile 128x36 (aliases sB)
    __syncthreads();
    unsigned short* ctile = sB;
    float bv[2];
    #pragma unroll
    for (int ni = 0; ni < 2; ++ni) bv[ni] = bias[n0 + ni * 16 + lq];
    #pragma unroll
    for (int mi = 0; mi < 2; ++mi)
        #pragma unroll
        for (int ni = 0; ni < 2; ++ni)
            #pragma unroll
            for (int r = 0; r < 4; ++r) {
                float v = fmaxf(acc[mi][ni][r] + bv[ni], 0.f);
                ctile[(wave * 32 + mi * 16 + quad * 4 + r) * 36 + ni * 16 + lq] = f2bf(v);
            }
    __syncthreads();

    // store 128 rows x 32 cols + atomic row-norm partials
    #pragma unroll
    for (int it = 0; it < 2; ++it) {
        int flat = it * 256 + t;
        int row = flat >> 2, seg = flat & 3;
        int gm = m0 + row;
        if (gm < M) {
            bf16x8 v = *(const bf16x8*)&ctile[row * 36 + seg * 8];
            *(bf16x8*)&Cout[(size_t)gm * N + n0 + seg * 8] = v;
            float s = 0.f;
            #pragma unroll
            for (int e = 0; e < 8; ++e) {
                float f = bf2f((unsigned short)v[e]);
                s = fmaf(f, f, s);
            }
            s += __shfl_down(s, 2, 4);
            s += __shfl_down(s, 1, 4);
            if (seg == 0) atomicAdd(&nrm[gm], s);
        }
    }
}

// ---------------------------------------------------------------------------
// Flash NCA, FULLY BARRIER-FREE: h-frags (16 i-rows per wave) live in 32
// VGPRs loaded once; B-frags direct from global (row layout = A layout);
// softmax tail of chunk c overlaps B-loads of chunk c+1 (no syncs at all).
// emb = combined embeddings [31024][128]: rows 0..N-1 = sh, N.. = h.
// ---------------------------------------------------------------------------
__global__ __launch_bounds__(256, 3) void nca_flash_mfma(
    const unsigned short* __restrict__ emb, const float* __restrict__ nrm,
    const float* __restrict__ y, float* __restrict__ gl, float* __restrict__ gy,
    int N, int jspan)
{
    const int t = threadIdx.x, wave = t >> 6, lane = t & 63;
    const int quad = lane >> 4, lq = lane & 15;
    const int i0 = blockIdx.x * 64;
    const int j0base = blockIdx.y * jspan;
    const int jend = min(j0base + jspan, N);
    const unsigned short* hb = emb + (size_t)N * 128;

    // A-frags once: wave's 16 i-rows, 4 k-chunks
    bf16x8 fa[4];
    #pragma unroll
    for (int kk = 0; kk < 4; ++kk)
        fa[kk] = *(const bf16x8*)&hb[(size_t)(i0 + wave * 16 + lq) * 128 + kk * 32 + quad * 8];
    float myh2[4];
    #pragma unroll
    for (int r = 0; r < 4; ++r) myh2[r] = nrm[N + i0 + wave * 16 + quad * 4 + r];

    float lacc[4] = {0.f, 0.f, 0.f, 0.f};
    float yacc[4] = {0.f, 0.f, 0.f, 0.f};

    #pragma unroll 2
    for (int c = 0; c < 4; ++c) {           // jspan = 512 = 4 chunks of 128
        int j0 = j0base + c * 128;
        if (j0 >= jend) break;

        f32x4 acc[8];
        #pragma unroll
        for (int jt = 0; jt < 8; ++jt) acc[jt] = (f32x4){0.f, 0.f, 0.f, 0.f};
        #pragma unroll
        for (int kk = 0; kk < 4; ++kk) {
            bf16x8 b[8];
            #pragma unroll
            for (int jt = 0; jt < 8; ++jt) {
                int jr = min(j0 + jt * 16 + lq, jend - 1);
                b[jt] = *(const bf16x8*)&emb[(size_t)jr * 128 + kk * 32 + quad * 8];
            }
            #pragma unroll
            for (int jt = 0; jt < 8; ++jt)
                acc[jt] = __builtin_amdgcn_mfma_f32_16x16x32_bf16(fa[kk], b[jt], acc[jt], 0, 0, 0);
        }

        #pragma unroll
        for (int jt = 0; jt < 8; ++jt) {
            int col = j0 + jt * 16 + lq;
            float ss = (col < jend) ? nrm[col] : 1e30f;   // OOB -> p=0
            float sy = (col < jend) ? y[col] : 0.f;
            #pragma unroll
            for (int r = 0; r < 4; ++r) {
                float d2 = myh2[r] + ss - 2.f * acc[jt][r];
                float d  = sqrtf(fmaxf(d2, 0.f) + EPSF);
                float p  = __expf(-d);
                lacc[r] += p;
                yacc[r]  = fmaf(p, sy, yacc[r]);
            }
        }
    }

    #pragma unroll
    for (int r = 0; r < 4; ++r) {
        #pragma unroll
        for (int off = 8; off > 0; off >>= 1) {
            lacc[r] += __shfl_down(lacc[r], off, 16);
            yacc[r] += __shfl_down(yacc[r], off, 16);
        }
    }
    if (lq == 0) {
        int rowl = wave * 16 + quad * 4;
        #pragma unroll
        for (int r = 0; r < 4; ++r) {
            atomicAdd(&gl[i0 + rowl + r], lacc[r]);
            atomicAdd(&gy[i0 + rowl + r], yacc[r]);
        }
    }
}

__global__ __launch_bounds__(256) void finalize_div(
    const float* __restrict__ gl, const float* __restrict__ gy,
    float* __restrict__ out, int B)
{
    int i = blockIdx.x * 256 + threadIdx.x;
    if (i < B) out[i] = gy[i] / gl[i];
}

// ---------------------------------------------------------------------------
extern "C" void kernel_launch(void* const* d_in, const int* in_sizes, int n_in,
                              void* d_out, int out_size, void* d_ws, size_t ws_size,
                              hipStream_t stream)
{
    const float* x    = (const float*)d_in[0];  // [1024,256]
    const float* subx = (const float*)d_in[1];  // [30000,256]
    const float* suby = (const float*)d_in[2];  // [30000]
    const float* W1   = (const float*)d_in[3];  // [256,512]
    const float* b1   = (const float*)d_in[4];  // [512]
    const float* W2   = (const float*)d_in[5];  // [512,128]
    const float* b2   = (const float*)d_in[6];  // [128]
    float* out = (float*)d_out;                 // [1024]

    const int B = 1024, N = 30000, D = 256, H1 = 512, H2 = 128;
    const int M = N + B;  // 31024 combined rows

    char* wsb = (char*)d_ws;
    size_t off = 0;
    auto alloc = [&](size_t bytes) -> char* {
        char* p = wsb + off;
        off += (bytes + 255) & ~(size_t)255;
        return p;
    };
    unsigned short* cxh  = (unsigned short*)alloc((size_t)M * D * 2);    // 15.9 MB
    unsigned short* cxl  = (unsigned short*)alloc((size_t)M * D * 2);
    unsigned short* w1hT = (unsigned short*)alloc((size_t)H1 * D * 2);
    unsigned short* w1lT = (unsigned short*)alloc((size_t)H1 * D * 2);
    unsigned short* w2hT = (unsigned short*)alloc((size_t)H2 * H1 * 2);
    unsigned short* w2lT = (unsigned short*)alloc((size_t)H2 * H1 * 2);
    unsigned short* z1   = (unsigned short*)alloc((size_t)M * H1 * 2);   // 31.8 MB
    unsigned short* emb  = (unsigned short*)alloc((size_t)M * H2 * 2);   // 7.9 MB
    float* nrm = (float*)alloc((size_t)M * 4);
    float* gl  = (float*)alloc((size_t)B * 4);
    float* gy  = (float*)alloc((size_t)B * 4);
    (void)ws_size; (void)in_sizes; (void)n_in; (void)out_size;

    dim3 blk(256);
    // prep: combined split (+ gl/gy/nrm zeroing), weight transpose-splits
    split_combined<<<dim3(M * D / 4 / 256), blk, 0, stream>>>(
        subx, x, cxh, cxl, gl, gy, nrm, M * D / 4, N, (M + 3) / 4);
    tsplit<<<dim3(D * H1 / 256), blk, 0, stream>>>(W1, w1hT, w1lT, 8, H1, D * H1);
    tsplit<<<dim3(H1 * H2 / 256), blk, 0, stream>>>(W2, w2hT, w2lT, 9, H2, H1 * H2);
    // layer 1 (3-term), stage-once barrier-free: 243 m x 8 n = 1944 blocks
    gemm_l1<<<dim3(((M + 127) / 128) * (H1 / 64)), blk, 0, stream>>>(
        cxh, cxl, w1hT, w1lT, b1, z1, M);
    // layer 2 (2-term) + atomic row norms: 243 m x 4 n = 972 blocks
    gemm_l2_norm<<<dim3(((M + 127) / 128) * (H2 / 32)), blk, 0, stream>>>(
        z1, w2hT, w2lT, b2, emb, nrm, M);
    // pairwise + softmax-weighted sum (barrier-free flash)
    const int JSPAN = 512;
    const int NSPLIT = (N + JSPAN - 1) / JSPAN;  // 59
    nca_flash_mfma<<<dim3(B / 64, NSPLIT), blk, 0, stream>>>(
        emb, nrm, suby, gl, gy, N, JSPAN);
    finalize_div<<<dim3(B / 256), blk, 0, stream>>>(gl, gy, out, B);
}

// Round 9
// 210.771 us; speedup vs baseline: 1.0628x; 1.0628x over previous
//
#include <hip/hip_runtime.h>
#include <hip/hip_bf16.h>
#include <math.h>

#define EPSF 1e-8f

typedef __attribute__((ext_vector_type(8))) short bf16x8;
typedef __attribute__((ext_vector_type(4))) float f32x4;

static __device__ __forceinline__ unsigned short f2bf(float f) {
    __hip_bfloat16 h = __float2bfloat16(f);
    return *reinterpret_cast<unsigned short*>(&h);
}
static __device__ __forceinline__ float bf2f(unsigned short u) {
    __hip_bfloat16 h;
    *reinterpret_cast<unsigned short*>(&h) = u;
    return __bfloat162float(h);
}

// ---------------------------------------------------------------------------
// FRAGMENT-ORDER tensor layout ("pre-swizzled", hipBLASLt-style):
// a [R,K] matrix is stored as 1KB chunks; chunk id = (r/16)*(K/32) + (k/32);
// within a chunk, lane l holds elements [r = l&15][k = (l>>4)*8 .. +8] at
// element offset l*8. A wave's MFMA A/B fragment load is then ONE
// global_load_dwordx4 at chunk_base + lane*16 -- fully coalesced (4 lines),
// vs 16 scattered lines for a row-major frag load (the R6/R8 mistake).
// ---------------------------------------------------------------------------

// ---------------------------------------------------------------------------
// Combined hi/lo split of [subx; x] -> fragment-order planes [M=31024, K=256].
// LDS repack: 32 rows/block, coalesced float4 reads, frag-scatter into LDS,
// contiguous 16B global stores. Also zeroes gl/gy.
// ---------------------------------------------------------------------------
__global__ __launch_bounds__(256) void split_frag(
    const float* __restrict__ subx, const float* __restrict__ x,
    unsigned short* __restrict__ H, unsigned short* __restrict__ L,
    float* __restrict__ gl, float* __restrict__ gy, int M, int nsubrow)
{
    __shared__ __align__(16) unsigned short sH[8192];  // 16 chunks
    __shared__ __align__(16) unsigned short sL[8192];
    const int t = threadIdx.x;
    const int gi = blockIdx.x * 256 + t;
    if (gi < 512) {
        float4 z = make_float4(0.f, 0.f, 0.f, 0.f);
        if (gi < 256) ((float4*)gl)[gi] = z;
        else          ((float4*)gy)[gi - 256] = z;
    }
    const int rbase = blockIdx.x * 32;
    const int rows = min(32, M - rbase);   // 32 or 16 (M % 16 == 0)

    #pragma unroll
    for (int it = 0; it < 8; ++it) {
        int flat = it * 256 + t;           // 0..2047
        int row = flat >> 6;               // 0..31
        int k = (flat & 63) * 4;           // 0..252
        if (row < rows) {
            int grow = rbase + row;
            const float* src = (grow < nsubrow)
                ? subx + (size_t)grow * 256 + k
                : x + (size_t)(grow - nsubrow) * 256 + k;
            float4 v = *(const float4*)src;
            unsigned short h0 = f2bf(v.x), h1 = f2bf(v.y), h2 = f2bf(v.z), h3 = f2bf(v.w);
            unsigned short l0 = f2bf(v.x - bf2f(h0));
            unsigned short l1 = f2bf(v.y - bf2f(h1));
            unsigned short l2 = f2bf(v.z - bf2f(h2));
            unsigned short l3 = f2bf(v.w - bf2f(h3));
            uint2 hp, lp;
            hp.x = ((unsigned)h1 << 16) | h0;  hp.y = ((unsigned)h3 << 16) | h2;
            lp.x = ((unsigned)l1 << 16) | l0;  lp.y = ((unsigned)l3 << 16) | l2;
            int chunk = (row >> 4) * 8 + (k >> 5);
            int lne = (row & 15) | (((k >> 3) & 3) << 4);
            int eoff = chunk * 512 + lne * 8 + (k & 7);
            *(uint2*)&sH[eoff] = hp;
            *(uint2*)&sL[eoff] = lp;
        }
    }
    __syncthreads();
    const int cvalid = (rows >> 4) * 8;
    const size_t base = (size_t)rbase * 256;   // chunk-contiguous
    #pragma unroll
    for (int it = 0; it < 4; ++it) {
        int flat = it * 256 + t;               // 0..1023
        if ((flat >> 6) < cvalid) {
            *(bf16x8*)&H[base + flat * 8] = *(const bf16x8*)&sH[flat * 8];
            *(bf16x8*)&L[base + flat * 8] = *(const bf16x8*)&sL[flat * 8];
        }
    }
}

// ---------------------------------------------------------------------------
// W [K,N] fp32 -> W^T hi/lo bf16 in fragment order [N rows, K cols].
// ---------------------------------------------------------------------------
__global__ __launch_bounds__(256) void tsplit_frag(
    const float* __restrict__ W, unsigned short* __restrict__ HT,
    unsigned short* __restrict__ LT, int kshift, int N, int total)
{
    int idx = blockIdx.x * 256 + threadIdx.x;
    if (idx >= total) return;
    int K = 1 << kshift;
    int n = idx >> kshift, k = idx & (K - 1);
    float w = W[(size_t)k * N + n];
    unsigned short h = f2bf(w);
    unsigned short l = f2bf(w - bf2f(h));
    int chunk = (n >> 4) * (K >> 5) + (k >> 5);
    int lne = (n & 15) | (((k >> 3) & 3) << 4);
    int eoff = chunk * 512 + lne * 8 + (k & 7);
    HT[eoff] = h;
    LT[eoff] = l;
}

// ---------------------------------------------------------------------------
// Layer-1: C = relu((Ah+Al)@(Bh+Bl)^T + bias), 3-term split-bf16 MFMA.
// All operands in fragment order -> zero input LDS, zero K-loop barriers,
// every frag load one coalesced dwordx4. 256x64 tile (wave = 64m x 64n,
// 48 MFMA : 16 loads per iter), fully-unrolled 8-iter K-loop. Epilogue
// repacks via ctile and emits z1 in fragment order (it is l2's A).
// ---------------------------------------------------------------------------
__global__ __launch_bounds__(256) void gemm_l1(
    const unsigned short* __restrict__ AhF, const unsigned short* __restrict__ AlF,
    const unsigned short* __restrict__ BhF, const unsigned short* __restrict__ BlF,
    const float* __restrict__ bias, unsigned short* __restrict__ z1F, int M)
{
    __shared__ __align__(16) unsigned short ctile[128 * 72];

    // XCD swizzle: contiguous newbid range per XCD
    const int nb = gridDim.x;
    const int per = nb >> 3, rem = nb & 7;
    const int xcd = blockIdx.x & 7, slot = blockIdx.x >> 3;
    const int newbid = xcd * per + min(xcd, rem) + slot;
    const int m0 = (newbid >> 3) * 256, n0 = (newbid & 7) * 64;

    const int t = threadIdx.x, wave = t >> 6, lane = t & 63;
    const int quad = lane >> 4, lq = lane & 15;
    const int lastch = (M >> 4) - 1;

    const unsigned short *pAh[4], *pAl[4], *pBh[4], *pBl[4];
    #pragma unroll
    for (int i = 0; i < 4; ++i) {
        int mc = min((m0 >> 4) + wave * 4 + i, lastch);
        pAh[i] = AhF + (size_t)mc * 4096 + lane * 8;   // K/32=8 chunks per row-grp
        pAl[i] = AlF + (size_t)mc * 4096 + lane * 8;
        int nc = (n0 >> 4) + i;
        pBh[i] = BhF + (size_t)nc * 4096 + lane * 8;
        pBl[i] = BlF + (size_t)nc * 4096 + lane * 8;
    }

    f32x4 acc[4][4];
    #pragma unroll
    for (int i = 0; i < 4; ++i)
        #pragma unroll
        for (int j = 0; j < 4; ++j) acc[i][j] = (f32x4){0.f, 0.f, 0.f, 0.f};

    #pragma unroll
    for (int kc = 0; kc < 8; ++kc) {
        const int off = kc * 512;
        bf16x8 fAh[4], fAl[4], fBh[4], fBl[4];
        #pragma unroll
        for (int i = 0; i < 4; ++i) {
            fAh[i] = *(const bf16x8*)(pAh[i] + off);
            fAl[i] = *(const bf16x8*)(pAl[i] + off);
            fBh[i] = *(const bf16x8*)(pBh[i] + off);
            fBl[i] = *(const bf16x8*)(pBl[i] + off);
        }
        #pragma unroll
        for (int mi = 0; mi < 4; ++mi)
            #pragma unroll
            for (int ni = 0; ni < 4; ++ni) {
                f32x4 a = acc[mi][ni];
                a = __builtin_amdgcn_mfma_f32_16x16x32_bf16(fAh[mi], fBh[ni], a, 0, 0, 0);
                a = __builtin_amdgcn_mfma_f32_16x16x32_bf16(fAh[mi], fBl[ni], a, 0, 0, 0);
                a = __builtin_amdgcn_mfma_f32_16x16x32_bf16(fAl[mi], fBh[ni], a, 0, 0, 0);
                acc[mi][ni] = a;
            }
    }

    // epilogue: 2 passes of 128 rows; bias+relu+round, frag-order z1 stores
    float bv[4];
    #pragma unroll
    for (int ni = 0; ni < 4; ++ni) bv[ni] = bias[n0 + ni * 16 + lq];
    #pragma unroll
    for (int p = 0; p < 2; ++p) {
        __syncthreads();
        if ((wave >> 1) == p) {
            int lr0 = (wave & 1) * 64;
            #pragma unroll
            for (int mi = 0; mi < 4; ++mi)
                #pragma unroll
                for (int ni = 0; ni < 4; ++ni)
                    #pragma unroll
                    for (int r = 0; r < 4; ++r) {
                        float v = fmaxf(acc[mi][ni][r] + bv[ni], 0.f);
                        ctile[(lr0 + mi * 16 + quad * 4 + r) * 72 + ni * 16 + lq] = f2bf(v);
                    }
        }
        __syncthreads();
        #pragma unroll
        for (int it = 0; it < 4; ++it) {
            int flat = it * 256 + t;           // 0..1023 = 16 chunks x 64
            int c = flat >> 6, l = flat & 63;
            int mcl = c >> 1, kc2 = c & 1;
            int gmc = (m0 >> 4) + p * 8 + mcl;
            if (gmc * 16 < M) {
                bf16x8 v = *(const bf16x8*)&ctile[(mcl * 16 + (l & 15)) * 72 + kc2 * 32 + (l >> 4) * 8];
                *(bf16x8*)&z1F[((size_t)gmc * 16 + (n0 >> 5) + kc2) * 512 + l * 8] = v;
            }
        }
    }
}

// ---------------------------------------------------------------------------
// Layer-2: C = relu(A@(Bh+Bl)^T + bias), 2-term split on W2. Fragment-order
// A (z1) and B (W2^T, 256KB, L2-hot); 128m x 128n (full width) per block;
// zero input LDS, zero K-loop barriers. Epilogue: frag-order emb + exact
// per-row norms (block owns all cols -> no atomics).
// ---------------------------------------------------------------------------
__global__ __launch_bounds__(256) void gemm_l2_norm(
    const unsigned short* __restrict__ AF,
    const unsigned short* __restrict__ BhF, const unsigned short* __restrict__ BlF,
    const float* __restrict__ bias, unsigned short* __restrict__ embF,
    float* __restrict__ nrm, int M)
{
    __shared__ __align__(16) unsigned short ctile[128 * 136];
    const int m0 = blockIdx.x * 128;
    const int t = threadIdx.x, wave = t >> 6, lane = t & 63;
    const int quad = lane >> 4, lq = lane & 15;
    const int lastch = (M >> 4) - 1;

    const unsigned short* pA[2];
    #pragma unroll
    for (int i = 0; i < 2; ++i) {
        int mc = min((m0 >> 4) + wave * 2 + i, lastch);
        pA[i] = AF + (size_t)mc * 8192 + lane * 8;     // K/32=16 chunks per grp
    }
    const unsigned short *pBh[8], *pBl[8];
    #pragma unroll
    for (int i = 0; i < 8; ++i) {
        pBh[i] = BhF + (size_t)i * 8192 + lane * 8;
        pBl[i] = BlF + (size_t)i * 8192 + lane * 8;
    }

    f32x4 acc[2][8];
    #pragma unroll
    for (int i = 0; i < 2; ++i)
        #pragma unroll
        for (int j = 0; j < 8; ++j) acc[i][j] = (f32x4){0.f, 0.f, 0.f, 0.f};

    #pragma unroll 2
    for (int kc = 0; kc < 16; ++kc) {
        const int off = kc * 512;
        bf16x8 fA[2];
        #pragma unroll
        for (int i = 0; i < 2; ++i) fA[i] = *(const bf16x8*)(pA[i] + off);
        #pragma unroll
        for (int ni = 0; ni < 8; ++ni) {
            bf16x8 fBh = *(const bf16x8*)(pBh[ni] + off);
            bf16x8 fBl = *(const bf16x8*)(pBl[ni] + off);
            #pragma unroll
            for (int mi = 0; mi < 2; ++mi) {
                f32x4 a = acc[mi][ni];
                a = __builtin_amdgcn_mfma_f32_16x16x32_bf16(fA[mi], fBh, a, 0, 0, 0);
                a = __builtin_amdgcn_mfma_f32_16x16x32_bf16(fA[mi], fBl, a, 0, 0, 0);
                acc[mi][ni] = a;
            }
        }
    }

    float bv[8];
    #pragma unroll
    for (int ni = 0; ni < 8; ++ni) bv[ni] = bias[ni * 16 + lq];
    #pragma unroll
    for (int mi = 0; mi < 2; ++mi)
        #pragma unroll
        for (int ni = 0; ni < 8; ++ni)
            #pragma unroll
            for (int r = 0; r < 4; ++r) {
                float v = fmaxf(acc[mi][ni][r] + bv[ni], 0.f);
                ctile[(wave * 32 + mi * 16 + quad * 4 + r) * 136 + ni * 16 + lq] = f2bf(v);
            }
    __syncthreads();

    // frag-order emb stores: 8 mchunks x 4 kchunks = 32 chunks
    #pragma unroll
    for (int it = 0; it < 8; ++it) {
        int flat = it * 256 + t;               // 0..2047
        int c = flat >> 6, l = flat & 63;
        int mcl = c >> 2, kc4 = c & 3;
        int gmc = (m0 >> 4) + mcl;
        if (gmc * 16 < M) {
            bf16x8 v = *(const bf16x8*)&ctile[(mcl * 16 + (l & 15)) * 136 + kc4 * 32 + (l >> 4) * 8];
            *(bf16x8*)&embF[((size_t)gmc * 4 + kc4) * 512 + l * 8] = v;
        }
    }
    // exact row norms of the rounded values (same order as R3-R6: seg asc,
    // half0 + half1 via shfl pair)
    int row = t >> 1, half = t & 1, gm = m0 + row;
    float s = 0.f;
    if (gm < M) {
        #pragma unroll
        for (int seg = 0; seg < 8; ++seg) {
            bf16x8 v = *(const bf16x8*)&ctile[row * 136 + half * 64 + seg * 8];
            #pragma unroll
            for (int e = 0; e < 8; ++e) {
                float f = bf2f((unsigned short)v[e]);
                s = fmaf(f, f, s);
            }
        }
    }
    s += __shfl_down(s, 1);
    if (half == 0 && gm < M) nrm[gm] = s;
}

// ---------------------------------------------------------------------------
// Flash NCA: zero LDS, zero barriers. Fragment-order emb -> both A- and
// B-frags are single coalesced dwordx4 loads. i-tile 128 (wave owns 32 rows,
// A-frags persistent in 32 VGPRs), j-chunks of 128, jspan 256.
// emb rows 0..N-1 = sh, N..N+B-1 = h (N, B both multiples of 16).
// ---------------------------------------------------------------------------
__global__ __launch_bounds__(256) void nca_flash_mfma(
    const unsigned short* __restrict__ embF, const float* __restrict__ nrm,
    const float* __restrict__ y, float* __restrict__ gl, float* __restrict__ gy,
    int N)
{
    const int t = threadIdx.x, wave = t >> 6, lane = t & 63;
    const int quad = lane >> 4, lq = lane & 15;
    const int i0 = blockIdx.x * 128;
    const int j0base = blockIdx.y * 256;
    const int jend = min(j0base + 256, N);

    bf16x8 fa[2][4];
    float myh2[2][4];
    #pragma unroll
    for (int mi = 0; mi < 2; ++mi) {
        int hc = (N >> 4) + (i0 >> 4) + wave * 2 + mi;
        #pragma unroll
        for (int kk = 0; kk < 4; ++kk)
            fa[mi][kk] = *(const bf16x8*)&embF[((size_t)hc * 4 + kk) * 512 + lane * 8];
        #pragma unroll
        for (int r = 0; r < 4; ++r)
            myh2[mi][r] = nrm[N + i0 + wave * 32 + mi * 16 + quad * 4 + r];
    }

    float lacc[2][4] = {};
    float yacc[2][4] = {};

    #pragma unroll
    for (int c = 0; c < 2; ++c) {
        int j0 = j0base + c * 128;
        if (j0 < jend) {
            f32x4 acc[2][8];
            #pragma unroll
            for (int mi = 0; mi < 2; ++mi)
                #pragma unroll
                for (int jt = 0; jt < 8; ++jt) acc[mi][jt] = (f32x4){0.f, 0.f, 0.f, 0.f};
            #pragma unroll
            for (int kk = 0; kk < 4; ++kk) {
                bf16x8 b[8];
                #pragma unroll
                for (int jt = 0; jt < 8; ++jt)
                    b[jt] = *(const bf16x8*)&embF[(((size_t)(j0 >> 4) + jt) * 4 + kk) * 512 + lane * 8];
                #pragma unroll
                for (int jt = 0; jt < 8; ++jt)
                    #pragma unroll
                    for (int mi = 0; mi < 2; ++mi)
                        acc[mi][jt] = __builtin_amdgcn_mfma_f32_16x16x32_bf16(fa[mi][kk], b[jt], acc[mi][jt], 0, 0, 0);
            }
            #pragma unroll
            for (int jt = 0; jt < 8; ++jt) {
                int col = j0 + jt * 16 + lq;
                float ss = (col < jend) ? nrm[col] : 1e30f;   // OOB/overflow rows -> p=0
                float sy = (col < jend) ? y[col] : 0.f;
                #pragma unroll
                for (int mi = 0; mi < 2; ++mi)
                    #pragma unroll
                    for (int r = 0; r < 4; ++r) {
                        float d2 = myh2[mi][r] + ss - 2.f * acc[mi][jt][r];
                        float d  = sqrtf(fmaxf(d2, 0.f) + EPSF);
                        float p  = __expf(-d);
                        lacc[mi][r] += p;
                        yacc[mi][r]  = fmaf(p, sy, yacc[mi][r]);
                    }
            }
        }
    }

    #pragma unroll
    for (int mi = 0; mi < 2; ++mi)
        #pragma unroll
        for (int r = 0; r < 4; ++r) {
            #pragma unroll
            for (int off = 8; off > 0; off >>= 1) {
                lacc[mi][r] += __shfl_down(lacc[mi][r], off, 16);
                yacc[mi][r] += __shfl_down(yacc[mi][r], off, 16);
            }
        }
    if (lq == 0) {
        #pragma unroll
        for (int mi = 0; mi < 2; ++mi) {
            int row = i0 + wave * 32 + mi * 16 + quad * 4;
            #pragma unroll
            for (int r = 0; r < 4; ++r) {
                atomicAdd(&gl[row + r], lacc[mi][r]);
                atomicAdd(&gy[row + r], yacc[mi][r]);
            }
        }
    }
}

__global__ __launch_bounds__(256) void finalize_div(
    const float* __restrict__ gl, const float* __restrict__ gy,
    float* __restrict__ out, int B)
{
    int i = blockIdx.x * 256 + threadIdx.x;
    if (i < B) out[i] = gy[i] / gl[i];
}

// ---------------------------------------------------------------------------
extern "C" void kernel_launch(void* const* d_in, const int* in_sizes, int n_in,
                              void* d_out, int out_size, void* d_ws, size_t ws_size,
                              hipStream_t stream)
{
    const float* x    = (const float*)d_in[0];  // [1024,256]
    const float* subx = (const float*)d_in[1];  // [30000,256]
    const float* suby = (const float*)d_in[2];  // [30000]
    const float* W1   = (const float*)d_in[3];  // [256,512]
    const float* b1   = (const float*)d_in[4];  // [512]
    const float* W2   = (const float*)d_in[5];  // [512,128]
    const float* b2   = (const float*)d_in[6];  // [128]
    float* out = (float*)d_out;                 // [1024]

    const int B = 1024, N = 30000, D = 256, H1 = 512, H2 = 128;
    const int M = N + B;  // 31024 (multiple of 16)

    char* wsb = (char*)d_ws;
    size_t off = 0;
    auto alloc = [&](size_t bytes) -> char* {
        char* p = wsb + off;
        off += (bytes + 255) & ~(size_t)255;
        return p;
    };
    unsigned short* cxh  = (unsigned short*)alloc((size_t)M * D * 2);
    unsigned short* cxl  = (unsigned short*)alloc((size_t)M * D * 2);
    unsigned short* w1hT = (unsigned short*)alloc((size_t)H1 * D * 2);
    unsigned short* w1lT = (unsigned short*)alloc((size_t)H1 * D * 2);
    unsigned short* w2hT = (unsigned short*)alloc((size_t)H2 * H1 * 2);
    unsigned short* w2lT = (unsigned short*)alloc((size_t)H2 * H1 * 2);
    unsigned short* z1   = (unsigned short*)alloc((size_t)M * H1 * 2);
    unsigned short* emb  = (unsigned short*)alloc((size_t)M * H2 * 2);
    float* nrm = (float*)alloc((size_t)M * 4);
    float* gl  = (float*)alloc((size_t)B * 4);
    float* gy  = (float*)alloc((size_t)B * 4);
    (void)ws_size; (void)in_sizes; (void)n_in; (void)out_size;

    dim3 blk(256);
    // prep: frag-order splits
    split_frag<<<dim3((M + 31) / 32), blk, 0, stream>>>(subx, x, cxh, cxl, gl, gy, M, N);
    tsplit_frag<<<dim3(D * H1 / 256), blk, 0, stream>>>(W1, w1hT, w1lT, 8, H1, D * H1);
    tsplit_frag<<<dim3(H1 * H2 / 256), blk, 0, stream>>>(W2, w2hT, w2lT, 9, H2, H1 * H2);
    // layer 1: 122 m-tiles x 8 n-tiles = 976 blocks
    gemm_l1<<<dim3(((M + 255) / 256) * (H1 / 64)), blk, 0, stream>>>(
        cxh, cxl, w1hT, w1lT, b1, z1, M);
    // layer 2 + row norms: 243 blocks (full 128-col width each)
    gemm_l2_norm<<<dim3((M + 127) / 128), blk, 0, stream>>>(
        z1, w2hT, w2lT, b2, emb, nrm, M);
    // pairwise + softmax-weighted sum: 8 i-blocks x 118 j-splits
    nca_flash_mfma<<<dim3(B / 128, (N + 255) / 256), blk, 0, stream>>>(
        emb, nrm, suby, gl, gy, N);
    finalize_div<<<dim3(B / 256), blk, 0, stream>>>(gl, gy, out, B);
}

// Round 10
// 199.414 us; speedup vs baseline: 1.1234x; 1.0570x over previous
//
#include <hip/hip_runtime.h>
#include <hip/hip_bf16.h>
#include <math.h>

#define EPSF 1e-8f

typedef __attribute__((ext_vector_type(8))) short bf16x8;
typedef __attribute__((ext_vector_type(4))) float f32x4;

static __device__ __forceinline__ unsigned short f2bf(float f) {
    __hip_bfloat16 h = __float2bfloat16(f);
    return *reinterpret_cast<unsigned short*>(&h);
}
static __device__ __forceinline__ float bf2f(unsigned short u) {
    __hip_bfloat16 h;
    *reinterpret_cast<unsigned short*>(&h) = u;
    return __bfloat162float(h);
}

// async global->LDS, 16B/lane: wave-uniform LDS base + lane*16.
static __device__ __forceinline__ void async16(void* lds, const void* g) {
    __builtin_amdgcn_global_load_lds(
        (const __attribute__((address_space(1))) unsigned int*)g,
        (__attribute__((address_space(3))) unsigned int*)lds, 16, 0, 0);
}

// ---------------------------------------------------------------------------
// FRAGMENT-ORDER tensor layout (hipBLASLt-style pre-swizzle):
// a [R,K] matrix is stored as 1KB chunks; chunk id = (r/16)*(K/32) + (k/32);
// within a chunk, lane l holds elements [r = l&15][k = (l>>4)*8 .. +8] at
// element offset l*8. A wave's MFMA A/B frag load is ONE coalesced
// global_load_dwordx4 (or one async16 DMA + conflict-free ds_read_b128).
// ---------------------------------------------------------------------------

// ---------------------------------------------------------------------------
// Combined hi/lo split of [subx; x] -> fragment-order planes [M=31024, K=256].
// LDS repack: 32 rows/block, coalesced float4 reads, frag-scatter into LDS,
// contiguous 16B global stores. Also zeroes gl/gy.
// ---------------------------------------------------------------------------
__global__ __launch_bounds__(256) void split_frag(
    const float* __restrict__ subx, const float* __restrict__ x,
    unsigned short* __restrict__ H, unsigned short* __restrict__ L,
    float* __restrict__ gl, float* __restrict__ gy, int M, int nsubrow)
{
    __shared__ __align__(16) unsigned short sH[8192];  // 16 chunks
    __shared__ __align__(16) unsigned short sL[8192];
    const int t = threadIdx.x;
    const int gi = blockIdx.x * 256 + t;
    if (gi < 512) {
        float4 z = make_float4(0.f, 0.f, 0.f, 0.f);
        if (gi < 256) ((float4*)gl)[gi] = z;
        else          ((float4*)gy)[gi - 256] = z;
    }
    const int rbase = blockIdx.x * 32;
    const int rows = min(32, M - rbase);   // 32 or 16 (M % 16 == 0)

    #pragma unroll
    for (int it = 0; it < 8; ++it) {
        int flat = it * 256 + t;           // 0..2047
        int row = flat >> 6;               // 0..31
        int k = (flat & 63) * 4;           // 0..252
        if (row < rows) {
            int grow = rbase + row;
            const float* src = (grow < nsubrow)
                ? subx + (size_t)grow * 256 + k
                : x + (size_t)(grow - nsubrow) * 256 + k;
            float4 v = *(const float4*)src;
            unsigned short h0 = f2bf(v.x), h1 = f2bf(v.y), h2 = f2bf(v.z), h3 = f2bf(v.w);
            unsigned short l0 = f2bf(v.x - bf2f(h0));
            unsigned short l1 = f2bf(v.y - bf2f(h1));
            unsigned short l2 = f2bf(v.z - bf2f(h2));
            unsigned short l3 = f2bf(v.w - bf2f(h3));
            uint2 hp, lp;
            hp.x = ((unsigned)h1 << 16) | h0;  hp.y = ((unsigned)h3 << 16) | h2;
            lp.x = ((unsigned)l1 << 16) | l0;  lp.y = ((unsigned)l3 << 16) | l2;
            int chunk = (row >> 4) * 8 + (k >> 5);
            int lne = (row & 15) | (((k >> 3) & 3) << 4);
            int eoff = chunk * 512 + lne * 8 + (k & 7);
            *(uint2*)&sH[eoff] = hp;
            *(uint2*)&sL[eoff] = lp;
        }
    }
    __syncthreads();
    const int cvalid = (rows >> 4) * 8;
    const size_t base = (size_t)rbase * 256;   // chunk-contiguous
    #pragma unroll
    for (int it = 0; it < 4; ++it) {
        int flat = it * 256 + t;               // 0..1023
        if ((flat >> 6) < cvalid) {
            *(bf16x8*)&H[base + flat * 8] = *(const bf16x8*)&sH[flat * 8];
            *(bf16x8*)&L[base + flat * 8] = *(const bf16x8*)&sL[flat * 8];
        }
    }
}

// ---------------------------------------------------------------------------
// W [K,N] fp32 -> W^T hi/lo bf16 in fragment order [N rows, K cols].
// ---------------------------------------------------------------------------
__global__ __launch_bounds__(256) void tsplit_frag(
    const float* __restrict__ W, unsigned short* __restrict__ HT,
    unsigned short* __restrict__ LT, int kshift, int N, int total)
{
    int idx = blockIdx.x * 256 + threadIdx.x;
    if (idx >= total) return;
    int K = 1 << kshift;
    int n = idx >> kshift, k = idx & (K - 1);
    float w = W[(size_t)k * N + n];
    unsigned short h = f2bf(w);
    unsigned short l = f2bf(w - bf2f(h));
    int chunk = (n >> 4) * (K >> 5) + (k >> 5);
    int lne = (n & 15) | (((k >> 3) & 3) << 4);
    int eoff = chunk * 512 + lne * 8 + (k & 7);
    HT[eoff] = h;
    LT[eoff] = l;
}

// ---------------------------------------------------------------------------
// Layer-1: C = relu((Ah+Al)@(Bh+Bl)^T + bias), 3-term split-bf16 MFMA.
// Fragment-order operands -> zero input LDS, zero K-loop barriers, every
// frag load one coalesced dwordx4. 256x64 tile, fully-unrolled 8-iter
// K-loop. Epilogue emits z1 in fragment order.
// ---------------------------------------------------------------------------
__global__ __launch_bounds__(256) void gemm_l1(
    const unsigned short* __restrict__ AhF, const unsigned short* __restrict__ AlF,
    const unsigned short* __restrict__ BhF, const unsigned short* __restrict__ BlF,
    const float* __restrict__ bias, unsigned short* __restrict__ z1F, int M)
{
    __shared__ __align__(16) unsigned short ctile[128 * 72];

    const int nb = gridDim.x;
    const int per = nb >> 3, rem = nb & 7;
    const int xcd = blockIdx.x & 7, slot = blockIdx.x >> 3;
    const int newbid = xcd * per + min(xcd, rem) + slot;
    const int m0 = (newbid >> 3) * 256, n0 = (newbid & 7) * 64;

    const int t = threadIdx.x, wave = t >> 6, lane = t & 63;
    const int quad = lane >> 4, lq = lane & 15;
    const int lastch = (M >> 4) - 1;

    const unsigned short *pAh[4], *pAl[4], *pBh[4], *pBl[4];
    #pragma unroll
    for (int i = 0; i < 4; ++i) {
        int mc = min((m0 >> 4) + wave * 4 + i, lastch);
        pAh[i] = AhF + (size_t)mc * 4096 + lane * 8;   // K/32=8 chunks per row-grp
        pAl[i] = AlF + (size_t)mc * 4096 + lane * 8;
        int nc = (n0 >> 4) + i;
        pBh[i] = BhF + (size_t)nc * 4096 + lane * 8;
        pBl[i] = BlF + (size_t)nc * 4096 + lane * 8;
    }

    f32x4 acc[4][4];
    #pragma unroll
    for (int i = 0; i < 4; ++i)
        #pragma unroll
        for (int j = 0; j < 4; ++j) acc[i][j] = (f32x4){0.f, 0.f, 0.f, 0.f};

    #pragma unroll
    for (int kc = 0; kc < 8; ++kc) {
        const int off = kc * 512;
        bf16x8 fAh[4], fAl[4], fBh[4], fBl[4];
        #pragma unroll
        for (int i = 0; i < 4; ++i) {
            fAh[i] = *(const bf16x8*)(pAh[i] + off);
            fAl[i] = *(const bf16x8*)(pAl[i] + off);
            fBh[i] = *(const bf16x8*)(pBh[i] + off);
            fBl[i] = *(const bf16x8*)(pBl[i] + off);
        }
        #pragma unroll
        for (int mi = 0; mi < 4; ++mi)
            #pragma unroll
            for (int ni = 0; ni < 4; ++ni) {
                f32x4 a = acc[mi][ni];
                a = __builtin_amdgcn_mfma_f32_16x16x32_bf16(fAh[mi], fBh[ni], a, 0, 0, 0);
                a = __builtin_amdgcn_mfma_f32_16x16x32_bf16(fAh[mi], fBl[ni], a, 0, 0, 0);
                a = __builtin_amdgcn_mfma_f32_16x16x32_bf16(fAl[mi], fBh[ni], a, 0, 0, 0);
                acc[mi][ni] = a;
            }
    }

    float bv[4];
    #pragma unroll
    for (int ni = 0; ni < 4; ++ni) bv[ni] = bias[n0 + ni * 16 + lq];
    #pragma unroll
    for (int p = 0; p < 2; ++p) {
        __syncthreads();
        if ((wave >> 1) == p) {
            int lr0 = (wave & 1) * 64;
            #pragma unroll
            for (int mi = 0; mi < 4; ++mi)
                #pragma unroll
                for (int ni = 0; ni < 4; ++ni)
                    #pragma unroll
                    for (int r = 0; r < 4; ++r) {
                        float v = fmaxf(acc[mi][ni][r] + bv[ni], 0.f);
                        ctile[(lr0 + mi * 16 + quad * 4 + r) * 72 + ni * 16 + lq] = f2bf(v);
                    }
        }
        __syncthreads();
        #pragma unroll
        for (int it = 0; it < 4; ++it) {
            int flat = it * 256 + t;           // 0..1023 = 16 chunks x 64
            int c = flat >> 6, l = flat & 63;
            int mcl = c >> 1, kc2 = c & 1;
            int gmc = (m0 >> 4) + p * 8 + mcl;
            if (gmc * 16 < M) {
                bf16x8 v = *(const bf16x8*)&ctile[(mcl * 16 + (l & 15)) * 72 + kc2 * 32 + (l >> 4) * 8];
                *(bf16x8*)&z1F[((size_t)gmc * 16 + (n0 >> 5) + kc2) * 512 + l * 8] = v;
            }
        }
    }
}

// ---------------------------------------------------------------------------
// Layer-2: C = relu(A@(Bh+Bl)^T + bias), 2-term split on W2. Fragment-order
// A (z1) and B (W2^T, L2-hot); 128m x 128n per block; zero input LDS, zero
// K-loop barriers. Epilogue: frag-order emb + exact per-row norms.
// ---------------------------------------------------------------------------
__global__ __launch_bounds__(256) void gemm_l2_norm(
    const unsigned short* __restrict__ AF,
    const unsigned short* __restrict__ BhF, const unsigned short* __restrict__ BlF,
    const float* __restrict__ bias, unsigned short* __restrict__ embF,
    float* __restrict__ nrm, int M)
{
    __shared__ __align__(16) unsigned short ctile[128 * 136];
    const int m0 = blockIdx.x * 128;
    const int t = threadIdx.x, wave = t >> 6, lane = t & 63;
    const int quad = lane >> 4, lq = lane & 15;
    const int lastch = (M >> 4) - 1;

    const unsigned short* pA[2];
    #pragma unroll
    for (int i = 0; i < 2; ++i) {
        int mc = min((m0 >> 4) + wave * 2 + i, lastch);
        pA[i] = AF + (size_t)mc * 8192 + lane * 8;     // K/32=16 chunks per grp
    }
    const unsigned short *pBh[8], *pBl[8];
    #pragma unroll
    for (int i = 0; i < 8; ++i) {
        pBh[i] = BhF + (size_t)i * 8192 + lane * 8;
        pBl[i] = BlF + (size_t)i * 8192 + lane * 8;
    }

    f32x4 acc[2][8];
    #pragma unroll
    for (int i = 0; i < 2; ++i)
        #pragma unroll
        for (int j = 0; j < 8; ++j) acc[i][j] = (f32x4){0.f, 0.f, 0.f, 0.f};

    #pragma unroll 2
    for (int kc = 0; kc < 16; ++kc) {
        const int off = kc * 512;
        bf16x8 fA[2];
        #pragma unroll
        for (int i = 0; i < 2; ++i) fA[i] = *(const bf16x8*)(pA[i] + off);
        #pragma unroll
        for (int ni = 0; ni < 8; ++ni) {
            bf16x8 fBh = *(const bf16x8*)(pBh[ni] + off);
            bf16x8 fBl = *(const bf16x8*)(pBl[ni] + off);
            #pragma unroll
            for (int mi = 0; mi < 2; ++mi) {
                f32x4 a = acc[mi][ni];
                a = __builtin_amdgcn_mfma_f32_16x16x32_bf16(fA[mi], fBh, a, 0, 0, 0);
                a = __builtin_amdgcn_mfma_f32_16x16x32_bf16(fA[mi], fBl, a, 0, 0, 0);
                acc[mi][ni] = a;
            }
        }
    }

    float bv[8];
    #pragma unroll
    for (int ni = 0; ni < 8; ++ni) bv[ni] = bias[ni * 16 + lq];
    #pragma unroll
    for (int mi = 0; mi < 2; ++mi)
        #pragma unroll
        for (int ni = 0; ni < 8; ++ni)
            #pragma unroll
            for (int r = 0; r < 4; ++r) {
                float v = fmaxf(acc[mi][ni][r] + bv[ni], 0.f);
                ctile[(wave * 32 + mi * 16 + quad * 4 + r) * 136 + ni * 16 + lq] = f2bf(v);
            }
    __syncthreads();

    #pragma unroll
    for (int it = 0; it < 8; ++it) {
        int flat = it * 256 + t;               // 0..2047
        int c = flat >> 6, l = flat & 63;
        int mcl = c >> 2, kc4 = c & 3;
        int gmc = (m0 >> 4) + mcl;
        if (gmc * 16 < M) {
            bf16x8 v = *(const bf16x8*)&ctile[(mcl * 16 + (l & 15)) * 136 + kc4 * 32 + (l >> 4) * 8];
            *(bf16x8*)&embF[((size_t)gmc * 4 + kc4) * 512 + l * 8] = v;
        }
    }
    int row = t >> 1, half = t & 1, gm = m0 + row;
    float s = 0.f;
    if (gm < M) {
        #pragma unroll
        for (int seg = 0; seg < 8; ++seg) {
            bf16x8 v = *(const bf16x8*)&ctile[row * 136 + half * 64 + seg * 8];
            #pragma unroll
            for (int e = 0; e < 8; ++e) {
                float f = bf2f((unsigned short)v[e]);
                s = fmaf(f, f, s);
            }
        }
    }
    s += __shfl_down(s, 1);
    if (half == 0 && gm < M) nrm[gm] = s;
}

// ---------------------------------------------------------------------------
// Flash NCA v10: frag-order emb + async16 LDS staging (the R5+R9 synthesis).
// i-tile 64: wave's A-frags persistent in 16 VGPRs (coalesced dwordx4 loads).
// j-chunks of 128: 32 frag-order 1KB chunks staged via 8 async16/wave into
// 32KB LDS (contiguous in global = exact async16 pattern; ds_read_b128 of a
// chunk is conflict-free), shared by all 4 waves. One barrier-pair per chunk,
// amortized over 32 MFMAs + 32-elem softmax tail per wave; ~3.7 blocks/CU
// co-resident (33KB LDS) cover the drains.
// ---------------------------------------------------------------------------
__global__ __launch_bounds__(256) void nca_flash_mfma(
    const unsigned short* __restrict__ embF, const float* __restrict__ nrm,
    const float* __restrict__ y, float* __restrict__ gl, float* __restrict__ gy,
    int N, int jspan)
{
    __shared__ __align__(16) unsigned short sB[16384];  // 32 chunks = 128 j-rows
    __shared__ float s2s[128], ys[128];

    const int t = threadIdx.x, wave = t >> 6, lane = t & 63;
    const int quad = lane >> 4, lq = lane & 15;
    const int i0 = blockIdx.x * 64;
    const int j0base = blockIdx.y * jspan;
    const int jend = min(j0base + jspan, N);

    // A-frags once (h region starts at chunk N/16; N,i0 multiples of 16)
    bf16x8 fa[4];
    const int hc = ((N + i0) >> 4) + wave;
    #pragma unroll
    for (int kk = 0; kk < 4; ++kk)
        fa[kk] = *(const bf16x8*)&embF[((size_t)hc * 4 + kk) * 512 + lane * 8];
    float myh2[4];
    #pragma unroll
    for (int r = 0; r < 4; ++r) myh2[r] = nrm[N + i0 + wave * 16 + quad * 4 + r];

    float lacc[4] = {0.f, 0.f, 0.f, 0.f};
    float yacc[4] = {0.f, 0.f, 0.f, 0.f};

    for (int j0 = j0base; j0 < jend; j0 += 128) {
        __syncthreads();   // previous chunk fully consumed
        // stage 32 chunks (8 per wave); slot c = jt*4 + kk. Rows beyond jend
        // read into the h-region (in-bounds) and are masked by s2s=1e30.
        #pragma unroll
        for (int q = 0; q < 8; ++q) {
            int c = wave * 8 + q;
            async16(sB + c * 512,
                    embF + ((size_t)(j0 >> 4) * 4 + c) * 512 + lane * 8);
        }
        if (t < 128) {
            int j = j0 + t;
            s2s[t] = (j < jend) ? nrm[j] : 1e30f;   // OOB -> p = 0
            ys[t]  = (j < jend) ? y[j] : 0.f;
        }
        __syncthreads();   // staging drained

        f32x4 acc[8];
        #pragma unroll
        for (int jt = 0; jt < 8; ++jt) acc[jt] = (f32x4){0.f, 0.f, 0.f, 0.f};
        #pragma unroll
        for (int kk = 0; kk < 4; ++kk) {
            #pragma unroll
            for (int jt = 0; jt < 8; ++jt) {
                bf16x8 b = *(const bf16x8*)&sB[(jt * 4 + kk) * 512 + lane * 8];
                acc[jt] = __builtin_amdgcn_mfma_f32_16x16x32_bf16(fa[kk], b, acc[jt], 0, 0, 0);
            }
        }

        #pragma unroll
        for (int jt = 0; jt < 8; ++jt) {
            int col = jt * 16 + lq;
            float ss = s2s[col];
            float sy = ys[col];
            #pragma unroll
            for (int r = 0; r < 4; ++r) {
                float d2 = myh2[r] + ss - 2.f * acc[jt][r];
                float d  = sqrtf(fmaxf(d2, 0.f) + EPSF);
                float p  = __expf(-d);
                lacc[r] += p;
                yacc[r]  = fmaf(p, sy, yacc[r]);
            }
        }
    }

    #pragma unroll
    for (int r = 0; r < 4; ++r) {
        #pragma unroll
        for (int off = 8; off > 0; off >>= 1) {
            lacc[r] += __shfl_down(lacc[r], off, 16);
            yacc[r] += __shfl_down(yacc[r], off, 16);
        }
    }
    if (lq == 0) {
        int row = i0 + wave * 16 + quad * 4;
        #pragma unroll
        for (int r = 0; r < 4; ++r) {
            atomicAdd(&gl[row + r], lacc[r]);
            atomicAdd(&gy[row + r], yacc[r]);
        }
    }
}

__global__ __launch_bounds__(256) void finalize_div(
    const float* __restrict__ gl, const float* __restrict__ gy,
    float* __restrict__ out, int B)
{
    int i = blockIdx.x * 256 + threadIdx.x;
    if (i < B) out[i] = gy[i] / gl[i];
}

// ---------------------------------------------------------------------------
extern "C" void kernel_launch(void* const* d_in, const int* in_sizes, int n_in,
                              void* d_out, int out_size, void* d_ws, size_t ws_size,
                              hipStream_t stream)
{
    const float* x    = (const float*)d_in[0];  // [1024,256]
    const float* subx = (const float*)d_in[1];  // [30000,256]
    const float* suby = (const float*)d_in[2];  // [30000]
    const float* W1   = (const float*)d_in[3];  // [256,512]
    const float* b1   = (const float*)d_in[4];  // [512]
    const float* W2   = (const float*)d_in[5];  // [512,128]
    const float* b2   = (const float*)d_in[6];  // [128]
    float* out = (float*)d_out;                 // [1024]

    const int B = 1024, N = 30000, D = 256, H1 = 512, H2 = 128;
    const int M = N + B;  // 31024 (multiple of 16)

    char* wsb = (char*)d_ws;
    size_t off = 0;
    auto alloc = [&](size_t bytes) -> char* {
        char* p = wsb + off;
        off += (bytes + 255) & ~(size_t)255;
        return p;
    };
    unsigned short* cxh  = (unsigned short*)alloc((size_t)M * D * 2);
    unsigned short* cxl  = (unsigned short*)alloc((size_t)M * D * 2);
    unsigned short* w1hT = (unsigned short*)alloc((size_t)H1 * D * 2);
    unsigned short* w1lT = (unsigned short*)alloc((size_t)H1 * D * 2);
    unsigned short* w2hT = (unsigned short*)alloc((size_t)H2 * H1 * 2);
    unsigned short* w2lT = (unsigned short*)alloc((size_t)H2 * H1 * 2);
    unsigned short* z1   = (unsigned short*)alloc((size_t)M * H1 * 2);
    unsigned short* emb  = (unsigned short*)alloc((size_t)M * H2 * 2);
    float* nrm = (float*)alloc((size_t)M * 4);
    float* gl  = (float*)alloc((size_t)B * 4);
    float* gy  = (float*)alloc((size_t)B * 4);
    (void)ws_size; (void)in_sizes; (void)n_in; (void)out_size;

    dim3 blk(256);
    // prep: frag-order splits
    split_frag<<<dim3((M + 31) / 32), blk, 0, stream>>>(subx, x, cxh, cxl, gl, gy, M, N);
    tsplit_frag<<<dim3(D * H1 / 256), blk, 0, stream>>>(W1, w1hT, w1lT, 8, H1, D * H1);
    tsplit_frag<<<dim3(H1 * H2 / 256), blk, 0, stream>>>(W2, w2hT, w2lT, 9, H2, H1 * H2);
    // layer 1: 122 m-tiles x 8 n-tiles = 976 blocks
    gemm_l1<<<dim3(((M + 255) / 256) * (H1 / 64)), blk, 0, stream>>>(
        cxh, cxl, w1hT, w1lT, b1, z1, M);
    // layer 2 + row norms: 243 blocks
    gemm_l2_norm<<<dim3((M + 127) / 128), blk, 0, stream>>>(
        z1, w2hT, w2lT, b2, emb, nrm, M);
    // pairwise + softmax-weighted sum: 16 i-blocks x 59 j-splits
    const int JSPAN = 512;
    const int NSPLIT = (N + JSPAN - 1) / JSPAN;  // 59
    nca_flash_mfma<<<dim3(B / 64, NSPLIT), blk, 0, stream>>>(
        emb, nrm, suby, gl, gy, N, JSPAN);
    finalize_div<<<dim3(B / 256), blk, 0, stream>>>(gl, gy, out, B);
}

// Round 11
// 166.699 us; speedup vs baseline: 1.3438x; 1.1962x over previous
//
#include <hip/hip_runtime.h>
#include <hip/hip_bf16.h>
#include <math.h>

#define EPSF 1e-8f

typedef __attribute__((ext_vector_type(8))) short bf16x8;
typedef __attribute__((ext_vector_type(4))) float f32x4;

static __device__ __forceinline__ unsigned short f2bf(float f) {
    __hip_bfloat16 h = __float2bfloat16(f);
    return *reinterpret_cast<unsigned short*>(&h);
}
static __device__ __forceinline__ float bf2f(unsigned short u) {
    __hip_bfloat16 h;
    *reinterpret_cast<unsigned short*>(&h) = u;
    return __bfloat162float(h);
}

// async global->LDS, 16B/lane: wave-uniform LDS base + lane*16.
static __device__ __forceinline__ void async16(void* lds, const void* g) {
    __builtin_amdgcn_global_load_lds(
        (const __attribute__((address_space(1))) unsigned int*)g,
        (__attribute__((address_space(3))) unsigned int*)lds, 16, 0, 0);
}

// ---------------------------------------------------------------------------
// FRAGMENT-ORDER layout: [R,K] stored as 1KB chunks; chunk = (r/16)*(K/32)
// + (k/32); lane l holds [r=l&15][k=(l>>4)*8..+8] at elem offset l*8.
// Frag load = one coalesced dwordx4 / one async16 + conflict-free b128.
// ---------------------------------------------------------------------------

// ---------------------------------------------------------------------------
// Round [subx; x] to bf16 in fragment order [M=31024, K=256] (SINGLE plane:
// x lo-residual dropped -- W stays split, so the only new error is the
// 2^-9 input rounding, ~half the final-emb rounding). Zeroes gl/gy.
// ---------------------------------------------------------------------------
__global__ __launch_bounds__(256) void split_frag(
    const float* __restrict__ subx, const float* __restrict__ x,
    unsigned short* __restrict__ XF,
    float* __restrict__ gl, float* __restrict__ gy, int M, int nsubrow)
{
    __shared__ __align__(16) unsigned short sX[8192];  // 16 chunks
    const int t = threadIdx.x;
    const int gi = blockIdx.x * 256 + t;
    if (gi < 512) {
        float4 z = make_float4(0.f, 0.f, 0.f, 0.f);
        if (gi < 256) ((float4*)gl)[gi] = z;
        else          ((float4*)gy)[gi - 256] = z;
    }
    const int rbase = blockIdx.x * 32;
    const int rows = min(32, M - rbase);   // 32 or 16

    #pragma unroll
    for (int it = 0; it < 8; ++it) {
        int flat = it * 256 + t;           // 0..2047
        int row = flat >> 6;
        int k = (flat & 63) * 4;
        if (row < rows) {
            int grow = rbase + row;
            const float* src = (grow < nsubrow)
                ? subx + (size_t)grow * 256 + k
                : x + (size_t)(grow - nsubrow) * 256 + k;
            float4 v = *(const float4*)src;
            unsigned short h0 = f2bf(v.x), h1 = f2bf(v.y), h2 = f2bf(v.z), h3 = f2bf(v.w);
            uint2 hp;
            hp.x = ((unsigned)h1 << 16) | h0;  hp.y = ((unsigned)h3 << 16) | h2;
            int chunk = (row >> 4) * 8 + (k >> 5);
            int lne = (row & 15) | (((k >> 3) & 3) << 4);
            *(uint2*)&sX[chunk * 512 + lne * 8 + (k & 7)] = hp;
        }
    }
    __syncthreads();
    const int cvalid = (rows >> 4) * 8;
    const size_t base = (size_t)rbase * 256;
    #pragma unroll
    for (int it = 0; it < 4; ++it) {
        int flat = it * 256 + t;               // 0..1023
        if ((flat >> 6) < cvalid)
            *(bf16x8*)&XF[base + flat * 8] = *(const bf16x8*)&sX[flat * 8];
    }
}

// ---------------------------------------------------------------------------
// W [K,N] fp32 -> W^T hi/lo bf16 in fragment order [N rows, K cols].
// ---------------------------------------------------------------------------
__global__ __launch_bounds__(256) void tsplit_frag(
    const float* __restrict__ W, unsigned short* __restrict__ HT,
    unsigned short* __restrict__ LT, int kshift, int N, int total)
{
    int idx = blockIdx.x * 256 + threadIdx.x;
    if (idx >= total) return;
    int K = 1 << kshift;
    int n = idx >> kshift, k = idx & (K - 1);
    float w = W[(size_t)k * N + n];
    unsigned short h = f2bf(w);
    unsigned short l = f2bf(w - bf2f(h));
    int chunk = (n >> 4) * (K >> 5) + (k >> 5);
    int lne = (n & 15) | (((k >> 3) & 3) << 4);
    int eoff = chunk * 512 + lne * 8 + (k & 7);
    HT[eoff] = h;
    LT[eoff] = l;
}

// ---------------------------------------------------------------------------
// Layer-1: z1 = relu(X@(Bh+Bl)^T + bias), 2-term split-bf16 MFMA (X single
// plane). R10-flash template: frag-order operands, per-iter async16 staging
// of A+B into LDS (24 chunks, conflict-free b128 reads), 128x128 tile,
// BK=32, 8 iters, 32 MFMA : 12 ds_read per wave-iter. Epilogue emits z1
// in fragment order via ctile.
// ---------------------------------------------------------------------------
__global__ __launch_bounds__(256) void gemm_l1(
    const unsigned short* __restrict__ XF,
    const unsigned short* __restrict__ BhF, const unsigned short* __restrict__ BlF,
    const float* __restrict__ bias, unsigned short* __restrict__ z1F, int M)
{
    __shared__ __align__(16) unsigned short smem[17408];  // stage 24KB | ctile 128x136
    unsigned short* sA  = smem;           // 8 chunks
    unsigned short* sBh = smem + 4096;    // 8 chunks
    unsigned short* sBl = smem + 8192;    // 8 chunks

    // XCD swizzle: contiguous newbid range per XCD
    const int nb = gridDim.x;
    const int per = nb >> 3, rem = nb & 7;
    const int xcd = blockIdx.x & 7, slot = blockIdx.x >> 3;
    const int newbid = xcd * per + min(xcd, rem) + slot;
    const int m0 = (newbid >> 2) * 128, n0 = (newbid & 3) * 128;

    const int t = threadIdx.x, wave = t >> 6, lane = t & 63;
    const int quad = lane >> 4, lq = lane & 15;
    const int mhalf = wave >> 1, nhalf = wave & 1;
    const int lastch = (M >> 4) - 1;

    // staging source chunk ids (per-iter offset = kc)
    const unsigned short* gsrc[6];
    unsigned short* ldst[6];
    #pragma unroll
    for (int q = 0; q < 6; ++q) {
        int c = wave * 6 + q;              // 0..23
        if (c < 8) {
            int mc = min((m0 >> 4) + c, lastch);
            gsrc[q] = XF + (size_t)mc * 4096 + lane * 8;        // 8 kch per mch
            ldst[q] = sA + c * 512;
        } else if (c < 16) {
            int nc = (n0 >> 4) + (c - 8);
            gsrc[q] = BhF + (size_t)nc * 4096 + lane * 8;
            ldst[q] = sBh + (c - 8) * 512;
        } else {
            int nc = (n0 >> 4) + (c - 16);
            gsrc[q] = BlF + (size_t)nc * 4096 + lane * 8;
            ldst[q] = sBl + (c - 16) * 512;
        }
    }

    f32x4 acc[4][4];
    #pragma unroll
    for (int i = 0; i < 4; ++i)
        #pragma unroll
        for (int j = 0; j < 4; ++j) acc[i][j] = (f32x4){0.f, 0.f, 0.f, 0.f};

    #pragma unroll
    for (int kc = 0; kc < 8; ++kc) {
        __syncthreads();
        #pragma unroll
        for (int q = 0; q < 6; ++q) async16(ldst[q], gsrc[q] + kc * 512);
        __syncthreads();

        bf16x8 fA[4];
        #pragma unroll
        for (int mi = 0; mi < 4; ++mi)
            fA[mi] = *(const bf16x8*)&sA[(mhalf * 4 + mi) * 512 + lane * 8];
        #pragma unroll
        for (int ni = 0; ni < 4; ++ni) {
            bf16x8 fBh = *(const bf16x8*)&sBh[(nhalf * 4 + ni) * 512 + lane * 8];
            bf16x8 fBl = *(const bf16x8*)&sBl[(nhalf * 4 + ni) * 512 + lane * 8];
            #pragma unroll
            for (int mi = 0; mi < 4; ++mi) {
                f32x4 a = acc[mi][ni];
                a = __builtin_amdgcn_mfma_f32_16x16x32_bf16(fA[mi], fBh, a, 0, 0, 0);
                a = __builtin_amdgcn_mfma_f32_16x16x32_bf16(fA[mi], fBl, a, 0, 0, 0);
                acc[mi][ni] = a;
            }
        }
    }

    // epilogue: bias+relu+round via 128x136 ctile, frag-order z1 stores
    __syncthreads();
    unsigned short* ctile = smem;
    float bv[4];
    #pragma unroll
    for (int ni = 0; ni < 4; ++ni) bv[ni] = bias[n0 + nhalf * 64 + ni * 16 + lq];
    #pragma unroll
    for (int mi = 0; mi < 4; ++mi)
        #pragma unroll
        for (int ni = 0; ni < 4; ++ni)
            #pragma unroll
            for (int r = 0; r < 4; ++r) {
                float v = fmaxf(acc[mi][ni][r] + bv[ni], 0.f);
                ctile[(mhalf * 64 + mi * 16 + quad * 4 + r) * 136 +
                      (nhalf * 64 + ni * 16 + lq)] = f2bf(v);
            }
    __syncthreads();
    #pragma unroll
    for (int it = 0; it < 8; ++it) {
        int flat = it * 256 + t;               // 0..2047 = 32 chunks x 64
        int c = flat >> 6, l = flat & 63;
        int mcl = c >> 2, kc4 = c & 3;
        int gmc = (m0 >> 4) + mcl;
        if (gmc * 16 < M) {
            bf16x8 v = *(const bf16x8*)&ctile[(mcl * 16 + (l & 15)) * 136 + kc4 * 32 + (l >> 4) * 8];
            *(bf16x8*)&z1F[((size_t)gmc * 16 + (n0 >> 5) + kc4) * 512 + l * 8] = v;
        }
    }
}

// ---------------------------------------------------------------------------
// Layer-2: emb = relu(z1@(Bh+Bl)^T + bias), 2-term split on W2. Same staged
// template: 64x128 tile (full width -> exact in-block row norms), BK=32,
// 16 iters, 20 chunks staged/iter. Epilogue: frag-order emb + norms.
// ---------------------------------------------------------------------------
__global__ __launch_bounds__(256) void gemm_l2_norm(
    const unsigned short* __restrict__ AF,
    const unsigned short* __restrict__ BhF, const unsigned short* __restrict__ BlF,
    const float* __restrict__ bias, unsigned short* __restrict__ embF,
    float* __restrict__ nrm, int M)
{
    __shared__ __align__(16) unsigned short smem[10240];  // stage 20KB | ctile 64x136
    unsigned short* sA  = smem;           // 4 chunks
    unsigned short* sBh = smem + 2048;    // 8 chunks
    unsigned short* sBl = smem + 6144;    // 8 chunks

    const int m0 = blockIdx.x * 64;
    const int t = threadIdx.x, wave = t >> 6, lane = t & 63;
    const int quad = lane >> 4, lq = lane & 15;
    const int lastch = (M >> 4) - 1;

    const unsigned short* gsrc[5];
    unsigned short* ldst[5];
    #pragma unroll
    for (int q = 0; q < 5; ++q) {
        int c = wave * 5 + q;              // 0..19
        if (c < 4) {
            int mc = min((m0 >> 4) + c, lastch);
            gsrc[q] = AF + (size_t)mc * 8192 + lane * 8;    // 16 kch per mch
            ldst[q] = sA + c * 512;
        } else if (c < 12) {
            gsrc[q] = BhF + (size_t)(c - 4) * 8192 + lane * 8;
            ldst[q] = sBh + (c - 4) * 512;
        } else {
            gsrc[q] = BlF + (size_t)(c - 12) * 8192 + lane * 8;
            ldst[q] = sBl + (c - 12) * 512;
        }
    }

    f32x4 acc[8];
    #pragma unroll
    for (int j = 0; j < 8; ++j) acc[j] = (f32x4){0.f, 0.f, 0.f, 0.f};

    #pragma unroll 4
    for (int kc = 0; kc < 16; ++kc) {
        __syncthreads();
        #pragma unroll
        for (int q = 0; q < 5; ++q) async16(ldst[q], gsrc[q] + kc * 512);
        __syncthreads();

        bf16x8 fA = *(const bf16x8*)&sA[wave * 512 + lane * 8];
        #pragma unroll
        for (int ni = 0; ni < 8; ++ni) {
            bf16x8 fBh = *(const bf16x8*)&sBh[ni * 512 + lane * 8];
            bf16x8 fBl = *(const bf16x8*)&sBl[ni * 512 + lane * 8];
            f32x4 a = acc[ni];
            a = __builtin_amdgcn_mfma_f32_16x16x32_bf16(fA, fBh, a, 0, 0, 0);
            a = __builtin_amdgcn_mfma_f32_16x16x32_bf16(fA, fBl, a, 0, 0, 0);
            acc[ni] = a;
        }
    }

    // epilogue via 64x136 ctile
    __syncthreads();
    unsigned short* ctile = smem;
    float bv[8];
    #pragma unroll
    for (int ni = 0; ni < 8; ++ni) bv[ni] = bias[ni * 16 + lq];
    #pragma unroll
    for (int ni = 0; ni < 8; ++ni)
        #pragma unroll
        for (int r = 0; r < 4; ++r) {
            float v = fmaxf(acc[ni][r] + bv[ni], 0.f);
            ctile[(wave * 16 + quad * 4 + r) * 136 + ni * 16 + lq] = f2bf(v);
        }
    __syncthreads();

    // frag-order emb stores: 4 mch x 4 kc4 = 16 chunks
    #pragma unroll
    for (int it = 0; it < 4; ++it) {
        int flat = it * 256 + t;               // 0..1023
        int c = flat >> 6, l = flat & 63;
        int mcl = c >> 2, kc4 = c & 3;
        int gmc = (m0 >> 4) + mcl;
        if (gmc * 16 < M) {
            bf16x8 v = *(const bf16x8*)&ctile[(mcl * 16 + (l & 15)) * 136 + kc4 * 32 + (l >> 4) * 8];
            *(bf16x8*)&embF[((size_t)gmc * 4 + kc4) * 512 + l * 8] = v;
        }
    }
    // exact row norms of the rounded values
    if (t < 128) {
        int row = t >> 1, half = t & 1, gm = m0 + row;
        float s = 0.f;
        if (gm < M) {
            #pragma unroll
            for (int seg = 0; seg < 8; ++seg) {
                bf16x8 v = *(const bf16x8*)&ctile[row * 136 + half * 64 + seg * 8];
                #pragma unroll
                for (int e = 0; e < 8; ++e) {
                    float f = bf2f((unsigned short)v[e]);
                    s = fmaf(f, f, s);
                }
            }
        }
        s += __shfl_down(s, 1);
        if (half == 0 && gm < M) nrm[gm] = s;
    }
}

// ---------------------------------------------------------------------------
// Flash NCA (unchanged from R10): frag-order emb + async16 LDS staging.
// ---------------------------------------------------------------------------
__global__ __launch_bounds__(256) void nca_flash_mfma(
    const unsigned short* __restrict__ embF, const float* __restrict__ nrm,
    const float* __restrict__ y, float* __restrict__ gl, float* __restrict__ gy,
    int N, int jspan)
{
    __shared__ __align__(16) unsigned short sB[16384];  // 32 chunks = 128 j-rows
    __shared__ float s2s[128], ys[128];

    const int t = threadIdx.x, wave = t >> 6, lane = t & 63;
    const int quad = lane >> 4, lq = lane & 15;
    const int i0 = blockIdx.x * 64;
    const int j0base = blockIdx.y * jspan;
    const int jend = min(j0base + jspan, N);

    bf16x8 fa[4];
    const int hc = ((N + i0) >> 4) + wave;
    #pragma unroll
    for (int kk = 0; kk < 4; ++kk)
        fa[kk] = *(const bf16x8*)&embF[((size_t)hc * 4 + kk) * 512 + lane * 8];
    float myh2[4];
    #pragma unroll
    for (int r = 0; r < 4; ++r) myh2[r] = nrm[N + i0 + wave * 16 + quad * 4 + r];

    float lacc[4] = {0.f, 0.f, 0.f, 0.f};
    float yacc[4] = {0.f, 0.f, 0.f, 0.f};

    for (int j0 = j0base; j0 < jend; j0 += 128) {
        __syncthreads();
        #pragma unroll
        for (int q = 0; q < 8; ++q) {
            int c = wave * 8 + q;
            async16(sB + c * 512,
                    embF + ((size_t)(j0 >> 4) * 4 + c) * 512 + lane * 8);
        }
        if (t < 128) {
            int j = j0 + t;
            s2s[t] = (j < jend) ? nrm[j] : 1e30f;   // OOB -> p = 0
            ys[t]  = (j < jend) ? y[j] : 0.f;
        }
        __syncthreads();

        f32x4 acc[8];
        #pragma unroll
        for (int jt = 0; jt < 8; ++jt) acc[jt] = (f32x4){0.f, 0.f, 0.f, 0.f};
        #pragma unroll
        for (int kk = 0; kk < 4; ++kk) {
            #pragma unroll
            for (int jt = 0; jt < 8; ++jt) {
                bf16x8 b = *(const bf16x8*)&sB[(jt * 4 + kk) * 512 + lane * 8];
                acc[jt] = __builtin_amdgcn_mfma_f32_16x16x32_bf16(fa[kk], b, acc[jt], 0, 0, 0);
            }
        }

        #pragma unroll
        for (int jt = 0; jt < 8; ++jt) {
            int col = jt * 16 + lq;
            float ss = s2s[col];
            float sy = ys[col];
            #pragma unroll
            for (int r = 0; r < 4; ++r) {
                float d2 = myh2[r] + ss - 2.f * acc[jt][r];
                float d  = sqrtf(fmaxf(d2, 0.f) + EPSF);
                float p  = __expf(-d);
                lacc[r] += p;
                yacc[r]  = fmaf(p, sy, yacc[r]);
            }
        }
    }

    #pragma unroll
    for (int r = 0; r < 4; ++r) {
        #pragma unroll
        for (int off = 8; off > 0; off >>= 1) {
            lacc[r] += __shfl_down(lacc[r], off, 16);
            yacc[r] += __shfl_down(yacc[r], off, 16);
        }
    }
    if (lq == 0) {
        int row = i0 + wave * 16 + quad * 4;
        #pragma unroll
        for (int r = 0; r < 4; ++r) {
            atomicAdd(&gl[row + r], lacc[r]);
            atomicAdd(&gy[row + r], yacc[r]);
        }
    }
}

__global__ __launch_bounds__(256) void finalize_div(
    const float* __restrict__ gl, const float* __restrict__ gy,
    float* __restrict__ out, int B)
{
    int i = blockIdx.x * 256 + threadIdx.x;
    if (i < B) out[i] = gy[i] / gl[i];
}

// ---------------------------------------------------------------------------
extern "C" void kernel_launch(void* const* d_in, const int* in_sizes, int n_in,
                              void* d_out, int out_size, void* d_ws, size_t ws_size,
                              hipStream_t stream)
{
    const float* x    = (const float*)d_in[0];  // [1024,256]
    const float* subx = (const float*)d_in[1];  // [30000,256]
    const float* suby = (const float*)d_in[2];  // [30000]
    const float* W1   = (const float*)d_in[3];  // [256,512]
    const float* b1   = (const float*)d_in[4];  // [512]
    const float* W2   = (const float*)d_in[5];  // [512,128]
    const float* b2   = (const float*)d_in[6];  // [128]
    float* out = (float*)d_out;                 // [1024]

    const int B = 1024, N = 30000, D = 256, H1 = 512, H2 = 128;
    const int M = N + B;  // 31024 (multiple of 16)

    char* wsb = (char*)d_ws;
    size_t off = 0;
    auto alloc = [&](size_t bytes) -> char* {
        char* p = wsb + off;
        off += (bytes + 255) & ~(size_t)255;
        return p;
    };
    unsigned short* cx   = (unsigned short*)alloc((size_t)M * D * 2);   // single plane
    unsigned short* w1hT = (unsigned short*)alloc((size_t)H1 * D * 2);
    unsigned short* w1lT = (unsigned short*)alloc((size_t)H1 * D * 2);
    unsigned short* w2hT = (unsigned short*)alloc((size_t)H2 * H1 * 2);
    unsigned short* w2lT = (unsigned short*)alloc((size_t)H2 * H1 * 2);
    unsigned short* z1   = (unsigned short*)alloc((size_t)M * H1 * 2);
    unsigned short* emb  = (unsigned short*)alloc((size_t)M * H2 * 2);
    float* nrm = (float*)alloc((size_t)M * 4);
    float* gl  = (float*)alloc((size_t)B * 4);
    float* gy  = (float*)alloc((size_t)B * 4);
    (void)ws_size; (void)in_sizes; (void)n_in; (void)out_size;

    dim3 blk(256);
    // prep
    split_frag<<<dim3((M + 31) / 32), blk, 0, stream>>>(subx, x, cx, gl, gy, M, N);
    tsplit_frag<<<dim3(D * H1 / 256), blk, 0, stream>>>(W1, w1hT, w1lT, 8, H1, D * H1);
    tsplit_frag<<<dim3(H1 * H2 / 256), blk, 0, stream>>>(W2, w2hT, w2lT, 9, H2, H1 * H2);
    // layer 1: 243 m-tiles x 4 n-tiles = 972 blocks
    gemm_l1<<<dim3(((M + 127) / 128) * (H1 / 128)), blk, 0, stream>>>(
        cx, w1hT, w1lT, b1, z1, M);
    // layer 2 + row norms: 485 blocks
    gemm_l2_norm<<<dim3((M + 63) / 64), blk, 0, stream>>>(
        z1, w2hT, w2lT, b2, emb, nrm, M);
    // pairwise + softmax-weighted sum: 16 i-blocks x 59 j-splits
    const int JSPAN = 512;
    const int NSPLIT = (N + JSPAN - 1) / JSPAN;  // 59
    nca_flash_mfma<<<dim3(B / 64, NSPLIT), blk, 0, stream>>>(
        emb, nrm, suby, gl, gy, N, JSPAN);
    finalize_div<<<dim3(B / 256), blk, 0, stream>>>(gl, gy, out, B);
}

// Round 12
// 157.497 us; speedup vs baseline: 1.4223x; 1.0584x over previous
//
#include <hip/hip_runtime.h>
#include <hip/hip_bf16.h>
#include <math.h>

#define EPSF 1e-8f

typedef __attribute__((ext_vector_type(8))) short bf16x8;
typedef __attribute__((ext_vector_type(4))) float f32x4;

static __device__ __forceinline__ unsigned short f2bf(float f) {
    __hip_bfloat16 h = __float2bfloat16(f);
    return *reinterpret_cast<unsigned short*>(&h);
}
static __device__ __forceinline__ float bf2f(unsigned short u) {
    __hip_bfloat16 h;
    *reinterpret_cast<unsigned short*>(&h) = u;
    return __bfloat162float(h);
}

// async global->LDS, 16B/lane: wave-uniform LDS base + lane*16.
static __device__ __forceinline__ void async16(void* lds, const void* g) {
    __builtin_amdgcn_global_load_lds(
        (const __attribute__((address_space(1))) unsigned int*)g,
        (__attribute__((address_space(3))) unsigned int*)lds, 16, 0, 0);
}

// ---------------------------------------------------------------------------
// FRAGMENT-ORDER layout: [R,K] stored as 1KB chunks; chunk = (r/16)*(K/32)
// + (k/32); lane l holds [r=l&15][k=(l>>4)*8..+8] at elem offset l*8.
// Frag load = one coalesced dwordx4 / one async16 + conflict-free b128.
// ---------------------------------------------------------------------------

// ---------------------------------------------------------------------------
// Fused prep (one launch):
//   region A (970 blocks): [subx;x] -> bf16 frag-order, + zero gl/gy/nrm
//   region B (512 blocks): W1 -> W1^T hi/lo frag-order
//   region C (256 blocks): W2 -> W2^T hi/lo frag-order
// ---------------------------------------------------------------------------
__global__ __launch_bounds__(256) void prep(
    const float* __restrict__ subx, const float* __restrict__ x,
    const float* __restrict__ W1, const float* __restrict__ W2,
    unsigned short* __restrict__ XF,
    unsigned short* __restrict__ w1h, unsigned short* __restrict__ w1l,
    unsigned short* __restrict__ w2h, unsigned short* __restrict__ w2l,
    float* __restrict__ gl, float* __restrict__ gy, float* __restrict__ nrm,
    int M, int nsubrow, int nsplitblk)
{
    __shared__ __align__(16) unsigned short sX[8192];
    const int t = threadIdx.x;
    const int b = blockIdx.x;

    if (b < nsplitblk) {
        int gi = b * 256 + t;
        float4 z = make_float4(0.f, 0.f, 0.f, 0.f);
        if (gi < 512) {
            if (gi < 256) ((float4*)gl)[gi] = z;
            else          ((float4*)gy)[gi - 256] = z;
        }
        if (gi < (M + 3) / 4) ((float4*)nrm)[gi] = z;

        const int rbase = b * 32;
        const int rows = min(32, M - rbase);
        #pragma unroll
        for (int it = 0; it < 8; ++it) {
            int flat = it * 256 + t;
            int row = flat >> 6;
            int k = (flat & 63) * 4;
            if (row < rows) {
                int grow = rbase + row;
                const float* src = (grow < nsubrow)
                    ? subx + (size_t)grow * 256 + k
                    : x + (size_t)(grow - nsubrow) * 256 + k;
                float4 v = *(const float4*)src;
                unsigned short h0 = f2bf(v.x), h1 = f2bf(v.y), h2 = f2bf(v.z), h3 = f2bf(v.w);
                uint2 hp;
                hp.x = ((unsigned)h1 << 16) | h0;  hp.y = ((unsigned)h3 << 16) | h2;
                int chunk = (row >> 4) * 8 + (k >> 5);
                int lne = (row & 15) | (((k >> 3) & 3) << 4);
                *(uint2*)&sX[chunk * 512 + lne * 8 + (k & 7)] = hp;
            }
        }
        __syncthreads();
        const int cvalid = (rows >> 4) * 8;
        const size_t base = (size_t)rbase * 256;
        #pragma unroll
        for (int it = 0; it < 4; ++it) {
            int flat = it * 256 + t;
            if ((flat >> 6) < cvalid)
                *(bf16x8*)&XF[base + flat * 8] = *(const bf16x8*)&sX[flat * 8];
        }
    } else if (b < nsplitblk + 512) {
        // W1 [256,512] -> [512 rows, 256 k], kshift 8
        int idx = (b - nsplitblk) * 256 + t;
        int n = idx >> 8, k = idx & 255;
        float w = W1[(size_t)k * 512 + n];
        unsigned short h = f2bf(w);
        unsigned short l = f2bf(w - bf2f(h));
        int chunk = (n >> 4) * 8 + (k >> 5);
        int lne = (n & 15) | (((k >> 3) & 3) << 4);
        int eoff = chunk * 512 + lne * 8 + (k & 7);
        w1h[eoff] = h;
        w1l[eoff] = l;
    } else {
        // W2 [512,128] -> [128 rows, 512 k], kshift 9
        int idx = (b - nsplitblk - 512) * 256 + t;
        int n = idx >> 9, k = idx & 511;
        float w = W2[(size_t)k * 128 + n];
        unsigned short h = f2bf(w);
        unsigned short l = f2bf(w - bf2f(h));
        int chunk = (n >> 4) * 16 + (k >> 5);
        int lne = (n & 15) | (((k >> 3) & 3) << 4);
        int eoff = chunk * 512 + lne * 8 + (k & 7);
        w2h[eoff] = h;
        w2l[eoff] = l;
    }
}

// ---------------------------------------------------------------------------
// Layer-1: z1 = relu(X@(W1h+W1l)^T + bias). STAGE-ONCE + BARRIER-FREE:
// whole 64-col B tile (hi+lo, 64KB) staged once via async16 (one drain);
// unrolled 8-iter K-loop = 2 coalesced frag-order A-loads + 8 conflict-free
// ds_read_b128 + 16 MFMA per wave, NO barriers. 3 barriers/block total.
// 128x64 tile, XCD-swizzled (A m-slice reused by 8 n-blocks per XCD L2).
// ---------------------------------------------------------------------------
__global__ __launch_bounds__(256) void gemm_l1(
    const unsigned short* __restrict__ XF,
    const unsigned short* __restrict__ BhF, const unsigned short* __restrict__ BlF,
    const float* __restrict__ bias, unsigned short* __restrict__ z1F, int M)
{
    __shared__ __align__(16) unsigned short sB[32768];  // 64 chunks; ctile aliases

    const int nb = gridDim.x;
    const int per = nb >> 3, rem = nb & 7;
    const int xcd = blockIdx.x & 7, slot = blockIdx.x >> 3;
    const int newbid = xcd * per + min(xcd, rem) + slot;
    const int m0 = (newbid >> 3) * 128, n0 = (newbid & 7) * 64;

    const int t = threadIdx.x, wave = t >> 6, lane = t & 63;
    const int quad = lane >> 4, lq = lane & 15;
    const int lastch = (M >> 4) - 1;

    // stage whole B tile once: chunks [plane(2)][nc(4)][kc(8)], 16 per wave
    #pragma unroll
    for (int q = 0; q < 16; ++q) {
        int c = wave * 16 + q;
        int plane = c >> 5, idx = c & 31, nc = idx >> 3, kc = idx & 7;
        const unsigned short* src = (plane ? BlF : BhF)
            + ((size_t)((n0 >> 4) + nc)) * 4096 + kc * 512 + lane * 8;
        async16(sB + c * 512, src);
    }

    // A frag pointers (coalesced frag-order direct loads)
    const unsigned short* pA[2];
    #pragma unroll
    for (int mi = 0; mi < 2; ++mi) {
        int mc = min((m0 >> 4) + wave * 2 + mi, lastch);
        pA[mi] = XF + (size_t)mc * 4096 + lane * 8;
    }

    f32x4 acc[2][4];
    #pragma unroll
    for (int i = 0; i < 2; ++i)
        #pragma unroll
        for (int j = 0; j < 4; ++j) acc[i][j] = (f32x4){0.f, 0.f, 0.f, 0.f};

    __syncthreads();   // single staging drain

    #pragma unroll
    for (int kc = 0; kc < 8; ++kc) {
        bf16x8 fA[2];
        #pragma unroll
        for (int mi = 0; mi < 2; ++mi)
            fA[mi] = *(const bf16x8*)(pA[mi] + kc * 512);
        #pragma unroll
        for (int ni = 0; ni < 4; ++ni) {
            bf16x8 fBh = *(const bf16x8*)&sB[(ni * 8 + kc) * 512 + lane * 8];
            bf16x8 fBl = *(const bf16x8*)&sB[16384 + (ni * 8 + kc) * 512 + lane * 8];
            #pragma unroll
            for (int mi = 0; mi < 2; ++mi) {
                f32x4 a = acc[mi][ni];
                a = __builtin_amdgcn_mfma_f32_16x16x32_bf16(fA[mi], fBh, a, 0, 0, 0);
                a = __builtin_amdgcn_mfma_f32_16x16x32_bf16(fA[mi], fBl, a, 0, 0, 0);
                acc[mi][ni] = a;
            }
        }
    }

    // epilogue: bias+relu+round via 128x72 ctile (aliases sB), frag-order z1
    __syncthreads();
    unsigned short* ctile = sB;
    float bv[4];
    #pragma unroll
    for (int ni = 0; ni < 4; ++ni) bv[ni] = bias[n0 + ni * 16 + lq];
    #pragma unroll
    for (int mi = 0; mi < 2; ++mi)
        #pragma unroll
        for (int ni = 0; ni < 4; ++ni)
            #pragma unroll
            for (int r = 0; r < 4; ++r) {
                float v = fmaxf(acc[mi][ni][r] + bv[ni], 0.f);
                ctile[(wave * 32 + mi * 16 + quad * 4 + r) * 72 + ni * 16 + lq] = f2bf(v);
            }
    __syncthreads();
    #pragma unroll
    for (int it = 0; it < 4; ++it) {
        int flat = it * 256 + t;               // 16 chunks x 64 lanes
        int c = flat >> 6, l = flat & 63;
        int mcl = c >> 1, kc2 = c & 1;
        int gmc = (m0 >> 4) + mcl;
        if (gmc * 16 < M) {
            bf16x8 v = *(const bf16x8*)&ctile[(mcl * 16 + (l & 15)) * 72 + kc2 * 32 + (l >> 4) * 8];
            *(bf16x8*)&z1F[((size_t)gmc * 16 + (n0 >> 5) + kc2) * 512 + l * 8] = v;
        }
    }
}

// ---------------------------------------------------------------------------
// Layer-2: emb = relu(z1@(W2h+W2l)^T + bias). Same stage-once template:
// 256x32 tile, 64KB W2-slice staged once, unrolled 16-iter barrier-free
// K-loop (4 A-loads + 4 ds + 16 MFMA per wave-iter). Epilogue: frag-order
// emb + per-row 32-col norm partials via atomicAdd (nrm zeroed in prep).
// ---------------------------------------------------------------------------
__global__ __launch_bounds__(256) void gemm_l2_norm(
    const unsigned short* __restrict__ AF,
    const unsigned short* __restrict__ BhF, const unsigned short* __restrict__ BlF,
    const float* __restrict__ bias, unsigned short* __restrict__ embF,
    float* __restrict__ nrm, int M)
{
    __shared__ __align__(16) unsigned short sB[32768];  // 64 chunks; ctile aliases

    const int nb = gridDim.x;
    const int per = nb >> 3, rem = nb & 7;
    const int xcd = blockIdx.x & 7, slot = blockIdx.x >> 3;
    const int newbid = xcd * per + min(xcd, rem) + slot;
    const int m0 = (newbid >> 2) * 256, n0 = (newbid & 3) * 32;

    const int t = threadIdx.x, wave = t >> 6, lane = t & 63;
    const int quad = lane >> 4, lq = lane & 15;
    const int lastch = (M >> 4) - 1;

    // stage W2 slice once: chunks [plane(2)][nc(2)][kc(16)], 16 per wave
    #pragma unroll
    for (int q = 0; q < 16; ++q) {
        int c = wave * 16 + q;
        int plane = c >> 5, idx = c & 31, nc = idx >> 4, kc = idx & 15;
        const unsigned short* src = (plane ? BlF : BhF)
            + ((size_t)((n0 >> 4) + nc)) * 8192 + kc * 512 + lane * 8;
        async16(sB + c * 512, src);
    }

    const unsigned short* pA[4];
    #pragma unroll
    for (int mi = 0; mi < 4; ++mi) {
        int mc = min((m0 >> 4) + wave * 4 + mi, lastch);
        pA[mi] = AF + (size_t)mc * 8192 + lane * 8;
    }

    f32x4 acc[4][2];
    #pragma unroll
    for (int i = 0; i < 4; ++i)
        #pragma unroll
        for (int j = 0; j < 2; ++j) acc[i][j] = (f32x4){0.f, 0.f, 0.f, 0.f};

    __syncthreads();   // single staging drain

    #pragma unroll 4
    for (int kc = 0; kc < 16; ++kc) {
        bf16x8 fA[4];
        #pragma unroll
        for (int mi = 0; mi < 4; ++mi)
            fA[mi] = *(const bf16x8*)(pA[mi] + kc * 512);
        #pragma unroll
        for (int ni = 0; ni < 2; ++ni) {
            bf16x8 fBh = *(const bf16x8*)&sB[(ni * 16 + kc) * 512 + lane * 8];
            bf16x8 fBl = *(const bf16x8*)&sB[16384 + (ni * 16 + kc) * 512 + lane * 8];
            #pragma unroll
            for (int mi = 0; mi < 4; ++mi) {
                f32x4 a = acc[mi][ni];
                a = __builtin_amdgcn_mfma_f32_16x16x32_bf16(fA[mi], fBh, a, 0, 0, 0);
                a = __builtin_amdgcn_mfma_f32_16x16x32_bf16(fA[mi], fBl, a, 0, 0, 0);
                acc[mi][ni] = a;
            }
        }
    }

    // epilogue via 256x36 ctile (aliases sB)
    __syncthreads();
    unsigned short* ctile = sB;
    float bv[2];
    #pragma unroll
    for (int ni = 0; ni < 2; ++ni) bv[ni] = bias[n0 + ni * 16 + lq];
    #pragma unroll
    for (int mi = 0; mi < 4; ++mi)
        #pragma unroll
        for (int ni = 0; ni < 2; ++ni)
            #pragma unroll
            for (int r = 0; r < 4; ++r) {
                float v = fmaxf(acc[mi][ni][r] + bv[ni], 0.f);
                ctile[(wave * 64 + mi * 16 + quad * 4 + r) * 36 + ni * 16 + lq] = f2bf(v);
            }
    __syncthreads();

    // frag-order emb stores: 16 mch chunks, single kc4 = n0/32
    #pragma unroll
    for (int it = 0; it < 4; ++it) {
        int flat = it * 256 + t;               // 16 chunks x 64 lanes
        int c = flat >> 6, l = flat & 63;
        int gmc = (m0 >> 4) + c;
        if (gmc * 16 < M) {
            bf16x8 v = *(const bf16x8*)&ctile[(c * 16 + (l & 15)) * 36 + (l >> 4) * 8];
            *(bf16x8*)&embF[((size_t)gmc * 4 + (n0 >> 5)) * 512 + l * 8] = v;
        }
    }
    // per-row norm partial over this block's 32 cols
    int gm = m0 + t;
    if (gm < M && t < 256) {
        float s = 0.f;
        #pragma unroll
        for (int seg = 0; seg < 4; ++seg) {
            bf16x8 v = *(const bf16x8*)&ctile[t * 36 + seg * 8];
            #pragma unroll
            for (int e = 0; e < 8; ++e) {
                float f = bf2f((unsigned short)v[e]);
                s = fmaf(f, f, s);
            }
        }
        atomicAdd(&nrm[gm], s);
    }
}

// ---------------------------------------------------------------------------
// Flash NCA (unchanged from R10): frag-order emb + async16 LDS staging.
// ---------------------------------------------------------------------------
__global__ __launch_bounds__(256) void nca_flash_mfma(
    const unsigned short* __restrict__ embF, const float* __restrict__ nrm,
    const float* __restrict__ y, float* __restrict__ gl, float* __restrict__ gy,
    int N, int jspan)
{
    __shared__ __align__(16) unsigned short sB[16384];  // 32 chunks = 128 j-rows
    __shared__ float s2s[128], ys[128];

    const int t = threadIdx.x, wave = t >> 6, lane = t & 63;
    const int quad = lane >> 4, lq = lane & 15;
    const int i0 = blockIdx.x * 64;
    const int j0base = blockIdx.y * jspan;
    const int jend = min(j0base + jspan, N);

    bf16x8 fa[4];
    const int hc = ((N + i0) >> 4) + wave;
    #pragma unroll
    for (int kk = 0; kk < 4; ++kk)
        fa[kk] = *(const bf16x8*)&embF[((size_t)hc * 4 + kk) * 512 + lane * 8];
    float myh2[4];
    #pragma unroll
    for (int r = 0; r < 4; ++r) myh2[r] = nrm[N + i0 + wave * 16 + quad * 4 + r];

    float lacc[4] = {0.f, 0.f, 0.f, 0.f};
    float yacc[4] = {0.f, 0.f, 0.f, 0.f};

    for (int j0 = j0base; j0 < jend; j0 += 128) {
        __syncthreads();
        #pragma unroll
        for (int q = 0; q < 8; ++q) {
            int c = wave * 8 + q;
            async16(sB + c * 512,
                    embF + ((size_t)(j0 >> 4) * 4 + c) * 512 + lane * 8);
        }
        if (t < 128) {
            int j = j0 + t;
            s2s[t] = (j < jend) ? nrm[j] : 1e30f;   // OOB -> p = 0
            ys[t]  = (j < jend) ? y[j] : 0.f;
        }
        __syncthreads();

        f32x4 acc[8];
        #pragma unroll
        for (int jt = 0; jt < 8; ++jt) acc[jt] = (f32x4){0.f, 0.f, 0.f, 0.f};
        #pragma unroll
        for (int kk = 0; kk < 4; ++kk) {
            #pragma unroll
            for (int jt = 0; jt < 8; ++jt) {
                bf16x8 b = *(const bf16x8*)&sB[(jt * 4 + kk) * 512 + lane * 8];
                acc[jt] = __builtin_amdgcn_mfma_f32_16x16x32_bf16(fa[kk], b, acc[jt], 0, 0, 0);
            }
        }

        #pragma unroll
        for (int jt = 0; jt < 8; ++jt) {
            int col = jt * 16 + lq;
            float ss = s2s[col];
            float sy = ys[col];
            #pragma unroll
            for (int r = 0; r < 4; ++r) {
                float d2 = myh2[r] + ss - 2.f * acc[jt][r];
                float d  = sqrtf(fmaxf(d2, 0.f) + EPSF);
                float p  = __expf(-d);
                lacc[r] += p;
                yacc[r]  = fmaf(p, sy, yacc[r]);
            }
        }
    }

    #pragma unroll
    for (int r = 0; r < 4; ++r) {
        #pragma unroll
        for (int off = 8; off > 0; off >>= 1) {
            lacc[r] += __shfl_down(lacc[r], off, 16);
            yacc[r] += __shfl_down(yacc[r], off, 16);
        }
    }
    if (lq == 0) {
        int row = i0 + wave * 16 + quad * 4;
        #pragma unroll
        for (int r = 0; r < 4; ++r) {
            atomicAdd(&gl[row + r], lacc[r]);
            atomicAdd(&gy[row + r], yacc[r]);
        }
    }
}

__global__ __launch_bounds__(256) void finalize_div(
    const float* __restrict__ gl, const float* __restrict__ gy,
    float* __restrict__ out, int B)
{
    int i = blockIdx.x * 256 + threadIdx.x;
    if (i < B) out[i] = gy[i] / gl[i];
}

// ---------------------------------------------------------------------------
extern "C" void kernel_launch(void* const* d_in, const int* in_sizes, int n_in,
                              void* d_out, int out_size, void* d_ws, size_t ws_size,
                              hipStream_t stream)
{
    const float* x    = (const float*)d_in[0];  // [1024,256]
    const float* subx = (const float*)d_in[1];  // [30000,256]
    const float* suby = (const float*)d_in[2];  // [30000]
    const float* W1   = (const float*)d_in[3];  // [256,512]
    const float* b1   = (const float*)d_in[4];  // [512]
    const float* W2   = (const float*)d_in[5];  // [512,128]
    const float* b2   = (const float*)d_in[6];  // [128]
    float* out = (float*)d_out;                 // [1024]

    const int B = 1024, N = 30000, D = 256, H1 = 512, H2 = 128;
    const int M = N + B;  // 31024

    char* wsb = (char*)d_ws;
    size_t off = 0;
    auto alloc = [&](size_t bytes) -> char* {
        char* p = wsb + off;
        off += (bytes + 255) & ~(size_t)255;
        return p;
    };
    unsigned short* cx   = (unsigned short*)alloc((size_t)M * D * 2);
    unsigned short* w1hT = (unsigned short*)alloc((size_t)H1 * D * 2);
    unsigned short* w1lT = (unsigned short*)alloc((size_t)H1 * D * 2);
    unsigned short* w2hT = (unsigned short*)alloc((size_t)H2 * H1 * 2);
    unsigned short* w2lT = (unsigned short*)alloc((size_t)H2 * H1 * 2);
    unsigned short* z1   = (unsigned short*)alloc((size_t)M * H1 * 2);
    unsigned short* emb  = (unsigned short*)alloc((size_t)M * H2 * 2);
    float* nrm = (float*)alloc((size_t)M * 4);
    float* gl  = (float*)alloc((size_t)B * 4);
    float* gy  = (float*)alloc((size_t)B * 4);
    (void)ws_size; (void)in_sizes; (void)n_in; (void)out_size;

    dim3 blk(256);
    // fused prep: split + both weight transposes + accumulator zeroing
    const int NSPLITBLK = (M + 31) / 32;                 // 970
    prep<<<dim3(NSPLITBLK + 512 + 256), blk, 0, stream>>>(
        subx, x, W1, W2, cx, w1hT, w1lT, w2hT, w2lT, gl, gy, nrm, M, N, NSPLITBLK);
    // layer 1: 243 m x 8 n = 1944 blocks, stage-once barrier-free
    gemm_l1<<<dim3(((M + 127) / 128) * (H1 / 64)), blk, 0, stream>>>(
        cx, w1hT, w1lT, b1, z1, M);
    // layer 2 + atomic row norms: 122 m x 4 n = 488 blocks
    gemm_l2_norm<<<dim3(((M + 255) / 256) * (H2 / 32)), blk, 0, stream>>>(
        z1, w2hT, w2lT, b2, emb, nrm, M);
    // pairwise + softmax-weighted sum: 16 i-blocks x 59 j-splits
    const int JSPAN = 512;
    const int NSPLIT = (N + JSPAN - 1) / JSPAN;  // 59
    nca_flash_mfma<<<dim3(B / 64, NSPLIT), blk, 0, stream>>>(
        emb, nrm, suby, gl, gy, N, JSPAN);
    finalize_div<<<dim3(B / 256), blk, 0, stream>>>(gl, gy, out, B);
}

// Round 13
// 152.774 us; speedup vs baseline: 1.4663x; 1.0309x over previous
//
#include <hip/hip_runtime.h>
#include <hip/hip_bf16.h>
#include <math.h>

#define EPSF 1e-8f

typedef __attribute__((ext_vector_type(8))) short bf16x8;
typedef __attribute__((ext_vector_type(4))) float f32x4;

static __device__ __forceinline__ unsigned short f2bf(float f) {
    __hip_bfloat16 h = __float2bfloat16(f);
    return *reinterpret_cast<unsigned short*>(&h);
}
static __device__ __forceinline__ float bf2f(unsigned short u) {
    __hip_bfloat16 h;
    *reinterpret_cast<unsigned short*>(&h) = u;
    return __bfloat162float(h);
}

// async global->LDS, 16B/lane: wave-uniform LDS base + lane*16.
static __device__ __forceinline__ void async16(void* lds, const void* g) {
    __builtin_amdgcn_global_load_lds(
        (const __attribute__((address_space(1))) unsigned int*)g,
        (__attribute__((address_space(3))) unsigned int*)lds, 16, 0, 0);
}

// ---------------------------------------------------------------------------
// FRAGMENT-ORDER layout: [R,K] stored as 1KB chunks; chunk = (r/16)*(K/32)
// + (k/32); lane l holds [r=l&15][k=(l>>4)*8..+8] at elem offset l*8.
// Frag load = one coalesced dwordx4 / one async16 + conflict-free b128.
// ---------------------------------------------------------------------------

// ---------------------------------------------------------------------------
// Fused prep (one launch):
//   region A: [subx;x] -> bf16 frag-order (single plane), + zero gl/gy/nrm
//   region B: W1 -> W1^T bf16 frag-order (SINGLE plane -- lo dropped; R11's
//             null result showed interior GEMM-operand rounding is masked
//             by the final emb rounding)
//   region C: W2 -> W2^T hi/lo frag-order (kept split: feeds emb directly)
// ---------------------------------------------------------------------------
__global__ __launch_bounds__(256) void prep(
    const float* __restrict__ subx, const float* __restrict__ x,
    const float* __restrict__ W1, const float* __restrict__ W2,
    unsigned short* __restrict__ XF,
    unsigned short* __restrict__ w1h,
    unsigned short* __restrict__ w2h, unsigned short* __restrict__ w2l,
    float* __restrict__ gl, float* __restrict__ gy, float* __restrict__ nrm,
    int M, int nsubrow, int nsplitblk)
{
    __shared__ __align__(16) unsigned short sX[8192];
    const int t = threadIdx.x;
    const int b = blockIdx.x;

    if (b < nsplitblk) {
        int gi = b * 256 + t;
        float4 z = make_float4(0.f, 0.f, 0.f, 0.f);
        if (gi < 512) {
            if (gi < 256) ((float4*)gl)[gi] = z;
            else          ((float4*)gy)[gi - 256] = z;
        }
        if (gi < (M + 3) / 4) ((float4*)nrm)[gi] = z;

        const int rbase = b * 32;
        const int rows = min(32, M - rbase);
        #pragma unroll
        for (int it = 0; it < 8; ++it) {
            int flat = it * 256 + t;
            int row = flat >> 6;
            int k = (flat & 63) * 4;
            if (row < rows) {
                int grow = rbase + row;
                const float* src = (grow < nsubrow)
                    ? subx + (size_t)grow * 256 + k
                    : x + (size_t)(grow - nsubrow) * 256 + k;
                float4 v = *(const float4*)src;
                unsigned short h0 = f2bf(v.x), h1 = f2bf(v.y), h2 = f2bf(v.z), h3 = f2bf(v.w);
                uint2 hp;
                hp.x = ((unsigned)h1 << 16) | h0;  hp.y = ((unsigned)h3 << 16) | h2;
                int chunk = (row >> 4) * 8 + (k >> 5);
                int lne = (row & 15) | (((k >> 3) & 3) << 4);
                *(uint2*)&sX[chunk * 512 + lne * 8 + (k & 7)] = hp;
            }
        }
        __syncthreads();
        const int cvalid = (rows >> 4) * 8;
        const size_t base = (size_t)rbase * 256;
        #pragma unroll
        for (int it = 0; it < 4; ++it) {
            int flat = it * 256 + t;
            if ((flat >> 6) < cvalid)
                *(bf16x8*)&XF[base + flat * 8] = *(const bf16x8*)&sX[flat * 8];
        }
    } else if (b < nsplitblk + 512) {
        // W1 [256,512] -> [512 rows, 256 k], single bf16 plane
        int idx = (b - nsplitblk) * 256 + t;
        int n = idx >> 8, k = idx & 255;
        float w = W1[(size_t)k * 512 + n];
        int chunk = (n >> 4) * 8 + (k >> 5);
        int lne = (n & 15) | (((k >> 3) & 3) << 4);
        w1h[chunk * 512 + lne * 8 + (k & 7)] = f2bf(w);
    } else {
        // W2 [512,128] -> [128 rows, 512 k], hi/lo split
        int idx = (b - nsplitblk - 512) * 256 + t;
        int n = idx >> 9, k = idx & 511;
        float w = W2[(size_t)k * 128 + n];
        unsigned short h = f2bf(w);
        unsigned short l = f2bf(w - bf2f(h));
        int chunk = (n >> 4) * 16 + (k >> 5);
        int lne = (n & 15) | (((k >> 3) & 3) << 4);
        int eoff = chunk * 512 + lne * 8 + (k & 7);
        w2h[eoff] = h;
        w2l[eoff] = l;
    }
}

// ---------------------------------------------------------------------------
// Layer-1: z1 = relu(X@W1^T + bias), SINGLE-plane bf16 MFMA.
// Stage-once + barrier-free: 32KB B tile (64 cols x K=256) staged once
// (one drain); unrolled 8-iter K-loop = 2 coalesced frag A-loads +
// 4 conflict-free ds_read_b128 + 8 MFMA per wave, no barriers.
// LDS 32KB -> ~5 blocks/CU (vs 2 in R12) for drain coverage.
// ---------------------------------------------------------------------------
__global__ __launch_bounds__(256) void gemm_l1(
    const unsigned short* __restrict__ XF,
    const unsigned short* __restrict__ BhF,
    const float* __restrict__ bias, unsigned short* __restrict__ z1F, int M)
{
    __shared__ __align__(16) unsigned short sB[16384];  // 32 chunks; ctile aliases

    const int nb = gridDim.x;
    const int per = nb >> 3, rem = nb & 7;
    const int xcd = blockIdx.x & 7, slot = blockIdx.x >> 3;
    const int newbid = xcd * per + min(xcd, rem) + slot;
    const int m0 = (newbid >> 3) * 128, n0 = (newbid & 7) * 64;

    const int t = threadIdx.x, wave = t >> 6, lane = t & 63;
    const int quad = lane >> 4, lq = lane & 15;
    const int lastch = (M >> 4) - 1;

    // stage B tile once: chunks [nc(4)][kc(8)], 8 per wave
    #pragma unroll
    for (int q = 0; q < 8; ++q) {
        int c = wave * 8 + q;
        int nc = c >> 3, kc = c & 7;
        const unsigned short* src = BhF
            + ((size_t)((n0 >> 4) + nc)) * 4096 + kc * 512 + lane * 8;
        async16(sB + c * 512, src);
    }

    const unsigned short* pA[2];
    #pragma unroll
    for (int mi = 0; mi < 2; ++mi) {
        int mc = min((m0 >> 4) + wave * 2 + mi, lastch);
        pA[mi] = XF + (size_t)mc * 4096 + lane * 8;
    }

    f32x4 acc[2][4];
    #pragma unroll
    for (int i = 0; i < 2; ++i)
        #pragma unroll
        for (int j = 0; j < 4; ++j) acc[i][j] = (f32x4){0.f, 0.f, 0.f, 0.f};

    __syncthreads();   // single staging drain

    #pragma unroll
    for (int kc = 0; kc < 8; ++kc) {
        bf16x8 fA[2];
        #pragma unroll
        for (int mi = 0; mi < 2; ++mi)
            fA[mi] = *(const bf16x8*)(pA[mi] + kc * 512);
        #pragma unroll
        for (int ni = 0; ni < 4; ++ni) {
            bf16x8 fB = *(const bf16x8*)&sB[(ni * 8 + kc) * 512 + lane * 8];
            #pragma unroll
            for (int mi = 0; mi < 2; ++mi)
                acc[mi][ni] = __builtin_amdgcn_mfma_f32_16x16x32_bf16(fA[mi], fB, acc[mi][ni], 0, 0, 0);
        }
    }

    // epilogue: bias+relu+round via 128x72 ctile (aliases sB), frag-order z1
    __syncthreads();
    unsigned short* ctile = sB;
    float bv[4];
    #pragma unroll
    for (int ni = 0; ni < 4; ++ni) bv[ni] = bias[n0 + ni * 16 + lq];
    #pragma unroll
    for (int mi = 0; mi < 2; ++mi)
        #pragma unroll
        for (int ni = 0; ni < 4; ++ni)
            #pragma unroll
            for (int r = 0; r < 4; ++r) {
                float v = fmaxf(acc[mi][ni][r] + bv[ni], 0.f);
                ctile[(wave * 32 + mi * 16 + quad * 4 + r) * 72 + ni * 16 + lq] = f2bf(v);
            }
    __syncthreads();
    #pragma unroll
    for (int it = 0; it < 4; ++it) {
        int flat = it * 256 + t;               // 16 chunks x 64 lanes
        int c = flat >> 6, l = flat & 63;
        int mcl = c >> 1, kc2 = c & 1;
        int gmc = (m0 >> 4) + mcl;
        if (gmc * 16 < M) {
            bf16x8 v = *(const bf16x8*)&ctile[(mcl * 16 + (l & 15)) * 72 + kc2 * 32 + (l >> 4) * 8];
            *(bf16x8*)&z1F[((size_t)gmc * 16 + (n0 >> 5) + kc2) * 512 + l * 8] = v;
        }
    }
}

// ---------------------------------------------------------------------------
// Layer-2: emb = relu(z1@(W2h+W2l)^T + bias), 2-term split (unchanged R12).
// 256x32 tile, 64KB W2-slice staged once, barrier-free 16-iter K-loop.
// Epilogue: frag-order emb + per-row 32-col norm partials via atomicAdd.
// ---------------------------------------------------------------------------
__global__ __launch_bounds__(256) void gemm_l2_norm(
    const unsigned short* __restrict__ AF,
    const unsigned short* __restrict__ BhF, const unsigned short* __restrict__ BlF,
    const float* __restrict__ bias, unsigned short* __restrict__ embF,
    float* __restrict__ nrm, int M)
{
    __shared__ __align__(16) unsigned short sB[32768];  // 64 chunks; ctile aliases

    const int nb = gridDim.x;
    const int per = nb >> 3, rem = nb & 7;
    const int xcd = blockIdx.x & 7, slot = blockIdx.x >> 3;
    const int newbid = xcd * per + min(xcd, rem) + slot;
    const int m0 = (newbid >> 2) * 256, n0 = (newbid & 3) * 32;

    const int t = threadIdx.x, wave = t >> 6, lane = t & 63;
    const int quad = lane >> 4, lq = lane & 15;
    const int lastch = (M >> 4) - 1;

    #pragma unroll
    for (int q = 0; q < 16; ++q) {
        int c = wave * 16 + q;
        int plane = c >> 5, idx = c & 31, nc = idx >> 4, kc = idx & 15;
        const unsigned short* src = (plane ? BlF : BhF)
            + ((size_t)((n0 >> 4) + nc)) * 8192 + kc * 512 + lane * 8;
        async16(sB + c * 512, src);
    }

    const unsigned short* pA[4];
    #pragma unroll
    for (int mi = 0; mi < 4; ++mi) {
        int mc = min((m0 >> 4) + wave * 4 + mi, lastch);
        pA[mi] = AF + (size_t)mc * 8192 + lane * 8;
    }

    f32x4 acc[4][2];
    #pragma unroll
    for (int i = 0; i < 4; ++i)
        #pragma unroll
        for (int j = 0; j < 2; ++j) acc[i][j] = (f32x4){0.f, 0.f, 0.f, 0.f};

    __syncthreads();   // single staging drain

    #pragma unroll 4
    for (int kc = 0; kc < 16; ++kc) {
        bf16x8 fA[4];
        #pragma unroll
        for (int mi = 0; mi < 4; ++mi)
            fA[mi] = *(const bf16x8*)(pA[mi] + kc * 512);
        #pragma unroll
        for (int ni = 0; ni < 2; ++ni) {
            bf16x8 fBh = *(const bf16x8*)&sB[(ni * 16 + kc) * 512 + lane * 8];
            bf16x8 fBl = *(const bf16x8*)&sB[16384 + (ni * 16 + kc) * 512 + lane * 8];
            #pragma unroll
            for (int mi = 0; mi < 4; ++mi) {
                f32x4 a = acc[mi][ni];
                a = __builtin_amdgcn_mfma_f32_16x16x32_bf16(fA[mi], fBh, a, 0, 0, 0);
                a = __builtin_amdgcn_mfma_f32_16x16x32_bf16(fA[mi], fBl, a, 0, 0, 0);
                acc[mi][ni] = a;
            }
        }
    }

    // epilogue via 256x36 ctile (aliases sB)
    __syncthreads();
    unsigned short* ctile = sB;
    float bv[2];
    #pragma unroll
    for (int ni = 0; ni < 2; ++ni) bv[ni] = bias[n0 + ni * 16 + lq];
    #pragma unroll
    for (int mi = 0; mi < 4; ++mi)
        #pragma unroll
        for (int ni = 0; ni < 2; ++ni)
            #pragma unroll
            for (int r = 0; r < 4; ++r) {
                float v = fmaxf(acc[mi][ni][r] + bv[ni], 0.f);
                ctile[(wave * 64 + mi * 16 + quad * 4 + r) * 36 + ni * 16 + lq] = f2bf(v);
            }
    __syncthreads();

    #pragma unroll
    for (int it = 0; it < 4; ++it) {
        int flat = it * 256 + t;
        int c = flat >> 6, l = flat & 63;
        int gmc = (m0 >> 4) + c;
        if (gmc * 16 < M) {
            bf16x8 v = *(const bf16x8*)&ctile[(c * 16 + (l & 15)) * 36 + (l >> 4) * 8];
            *(bf16x8*)&embF[((size_t)gmc * 4 + (n0 >> 5)) * 512 + l * 8] = v;
        }
    }
    int gm = m0 + t;
    if (gm < M) {
        float s = 0.f;
        #pragma unroll
        for (int seg = 0; seg < 4; ++seg) {
            bf16x8 v = *(const bf16x8*)&ctile[t * 36 + seg * 8];
            #pragma unroll
            for (int e = 0; e < 8; ++e) {
                float f = bf2f((unsigned short)v[e]);
                s = fmaf(f, f, s);
            }
        }
        atomicAdd(&nrm[gm], s);
    }
}

// ---------------------------------------------------------------------------
// Flash NCA (unchanged from R10): frag-order emb + async16 LDS staging.
// ---------------------------------------------------------------------------
__global__ __launch_bounds__(256) void nca_flash_mfma(
    const unsigned short* __restrict__ embF, const float* __restrict__ nrm,
    const float* __restrict__ y, float* __restrict__ gl, float* __restrict__ gy,
    int N, int jspan)
{
    __shared__ __align__(16) unsigned short sB[16384];  // 32 chunks = 128 j-rows
    __shared__ float s2s[128], ys[128];

    const int t = threadIdx.x, wave = t >> 6, lane = t & 63;
    const int quad = lane >> 4, lq = lane & 15;
    const int i0 = blockIdx.x * 64;
    const int j0base = blockIdx.y * jspan;
    const int jend = min(j0base + jspan, N);

    bf16x8 fa[4];
    const int hc = ((N + i0) >> 4) + wave;
    #pragma unroll
    for (int kk = 0; kk < 4; ++kk)
        fa[kk] = *(const bf16x8*)&embF[((size_t)hc * 4 + kk) * 512 + lane * 8];
    float myh2[4];
    #pragma unroll
    for (int r = 0; r < 4; ++r) myh2[r] = nrm[N + i0 + wave * 16 + quad * 4 + r];

    float lacc[4] = {0.f, 0.f, 0.f, 0.f};
    float yacc[4] = {0.f, 0.f, 0.f, 0.f};

    for (int j0 = j0base; j0 < jend; j0 += 128) {
        __syncthreads();
        #pragma unroll
        for (int q = 0; q < 8; ++q) {
            int c = wave * 8 + q;
            async16(sB + c * 512,
                    embF + ((size_t)(j0 >> 4) * 4 + c) * 512 + lane * 8);
        }
        if (t < 128) {
            int j = j0 + t;
            s2s[t] = (j < jend) ? nrm[j] : 1e30f;   // OOB -> p = 0
            ys[t]  = (j < jend) ? y[j] : 0.f;
        }
        __syncthreads();

        f32x4 acc[8];
        #pragma unroll
        for (int jt = 0; jt < 8; ++jt) acc[jt] = (f32x4){0.f, 0.f, 0.f, 0.f};
        #pragma unroll
        for (int kk = 0; kk < 4; ++kk) {
            #pragma unroll
            for (int jt = 0; jt < 8; ++jt) {
                bf16x8 b = *(const bf16x8*)&sB[(jt * 4 + kk) * 512 + lane * 8];
                acc[jt] = __builtin_amdgcn_mfma_f32_16x16x32_bf16(fa[kk], b, acc[jt], 0, 0, 0);
            }
        }

        #pragma unroll
        for (int jt = 0; jt < 8; ++jt) {
            int col = jt * 16 + lq;
            float ss = s2s[col];
            float sy = ys[col];
            #pragma unroll
            for (int r = 0; r < 4; ++r) {
                float d2 = myh2[r] + ss - 2.f * acc[jt][r];
                float d  = sqrtf(fmaxf(d2, 0.f) + EPSF);
                float p  = __expf(-d);
                lacc[r] += p;
                yacc[r]  = fmaf(p, sy, yacc[r]);
            }
        }
    }

    #pragma unroll
    for (int r = 0; r < 4; ++r) {
        #pragma unroll
        for (int off = 8; off > 0; off >>= 1) {
            lacc[r] += __shfl_down(lacc[r], off, 16);
            yacc[r] += __shfl_down(yacc[r], off, 16);
        }
    }
    if (lq == 0) {
        int row = i0 + wave * 16 + quad * 4;
        #pragma unroll
        for (int r = 0; r < 4; ++r) {
            atomicAdd(&gl[row + r], lacc[r]);
            atomicAdd(&gy[row + r], yacc[r]);
        }
    }
}

__global__ __launch_bounds__(256) void finalize_div(
    const float* __restrict__ gl, const float* __restrict__ gy,
    float* __restrict__ out, int B)
{
    int i = blockIdx.x * 256 + threadIdx.x;
    if (i < B) out[i] = gy[i] / gl[i];
}

// ---------------------------------------------------------------------------
extern "C" void kernel_launch(void* const* d_in, const int* in_sizes, int n_in,
                              void* d_out, int out_size, void* d_ws, size_t ws_size,
                              hipStream_t stream)
{
    const float* x    = (const float*)d_in[0];  // [1024,256]
    const float* subx = (const float*)d_in[1];  // [30000,256]
    const float* suby = (const float*)d_in[2];  // [30000]
    const float* W1   = (const float*)d_in[3];  // [256,512]
    const float* b1   = (const float*)d_in[4];  // [512]
    const float* W2   = (const float*)d_in[5];  // [512,128]
    const float* b2   = (const float*)d_in[6];  // [128]
    float* out = (float*)d_out;                 // [1024]

    const int B = 1024, N = 30000, D = 256, H1 = 512, H2 = 128;
    const int M = N + B;  // 31024

    char* wsb = (char*)d_ws;
    size_t off = 0;
    auto alloc = [&](size_t bytes) -> char* {
        char* p = wsb + off;
        off += (bytes + 255) & ~(size_t)255;
        return p;
    };
    unsigned short* cx   = (unsigned short*)alloc((size_t)M * D * 2);
    unsigned short* w1hT = (unsigned short*)alloc((size_t)H1 * D * 2);
    unsigned short* w2hT = (unsigned short*)alloc((size_t)H2 * H1 * 2);
    unsigned short* w2lT = (unsigned short*)alloc((size_t)H2 * H1 * 2);
    unsigned short* z1   = (unsigned short*)alloc((size_t)M * H1 * 2);
    unsigned short* emb  = (unsigned short*)alloc((size_t)M * H2 * 2);
    float* nrm = (float*)alloc((size_t)M * 4);
    float* gl  = (float*)alloc((size_t)B * 4);
    float* gy  = (float*)alloc((size_t)B * 4);
    (void)ws_size; (void)in_sizes; (void)n_in; (void)out_size;

    dim3 blk(256);
    // fused prep: split + weight transposes + accumulator zeroing
    const int NSPLITBLK = (M + 31) / 32;                 // 970
    prep<<<dim3(NSPLITBLK + 512 + 256), blk, 0, stream>>>(
        subx, x, W1, W2, cx, w1hT, w2hT, w2lT, gl, gy, nrm, M, N, NSPLITBLK);
    // layer 1 (single-plane W1): 243 m x 8 n = 1944 blocks
    gemm_l1<<<dim3(((M + 127) / 128) * (H1 / 64)), blk, 0, stream>>>(
        cx, w1hT, b1, z1, M);
    // layer 2 (split W2) + atomic row norms: 122 m x 4 n = 488 blocks
    gemm_l2_norm<<<dim3(((M + 255) / 256) * (H2 / 32)), blk, 0, stream>>>(
        z1, w2hT, w2lT, b2, emb, nrm, M);
    // pairwise + softmax-weighted sum: 16 i-blocks x 59 j-splits
    const int JSPAN = 512;
    const int NSPLIT = (N + JSPAN - 1) / JSPAN;  // 59
    nca_flash_mfma<<<dim3(B / 64, NSPLIT), blk, 0, stream>>>(
        emb, nrm, suby, gl, gy, N, JSPAN);
    finalize_div<<<dim3(B / 256), blk, 0, stream>>>(gl, gy, out, B);
}

// Round 14
// 148.179 us; speedup vs baseline: 1.5118x; 1.0310x over previous
//
#include <hip/hip_runtime.h>
#include <hip/hip_bf16.h>
#include <math.h>

#define EPSF 1e-8f

typedef __attribute__((ext_vector_type(8))) short bf16x8;
typedef __attribute__((ext_vector_type(4))) float f32x4;

static __device__ __forceinline__ unsigned short f2bf(float f) {
    __hip_bfloat16 h = __float2bfloat16(f);
    return *reinterpret_cast<unsigned short*>(&h);
}
static __device__ __forceinline__ float bf2f(unsigned short u) {
    __hip_bfloat16 h;
    *reinterpret_cast<unsigned short*>(&h) = u;
    return __bfloat162float(h);
}

// async global->LDS, 16B/lane: wave-uniform LDS base + lane*16.
static __device__ __forceinline__ void async16(void* lds, const void* g) {
    __builtin_amdgcn_global_load_lds(
        (const __attribute__((address_space(1))) unsigned int*)g,
        (__attribute__((address_space(3))) unsigned int*)lds, 16, 0, 0);
}

// ---------------------------------------------------------------------------
// FRAGMENT-ORDER layout: [R,K] stored as 1KB chunks; chunk = (r/16)*(K/32)
// + (k/32); lane l holds [r=l&15][k=(l>>4)*8..+8] at elem offset l*8.
// Frag load = one coalesced dwordx4 / one async16 + conflict-free b128.
// ---------------------------------------------------------------------------

// ---------------------------------------------------------------------------
// Fused prep (one launch):
//   region A: [subx;x] -> bf16 frag-order (single plane), + zero gl/gy/nrm
//   region B: W1 -> W1^T bf16 frag-order (single plane)
//   region C: W2 -> W2^T bf16 frag-order (single plane -- lo dropped R14;
//             R13's measured absmax DROP on removing W1l showed interior
//             roundings are dominated by the final emb rounding)
// ---------------------------------------------------------------------------
__global__ __launch_bounds__(256) void prep(
    const float* __restrict__ subx, const float* __restrict__ x,
    const float* __restrict__ W1, const float* __restrict__ W2,
    unsigned short* __restrict__ XF,
    unsigned short* __restrict__ w1h, unsigned short* __restrict__ w2h,
    float* __restrict__ gl, float* __restrict__ gy, float* __restrict__ nrm,
    int M, int nsubrow, int nsplitblk)
{
    __shared__ __align__(16) unsigned short sX[8192];
    const int t = threadIdx.x;
    const int b = blockIdx.x;

    if (b < nsplitblk) {
        int gi = b * 256 + t;
        float4 z = make_float4(0.f, 0.f, 0.f, 0.f);
        if (gi < 512) {
            if (gi < 256) ((float4*)gl)[gi] = z;
            else          ((float4*)gy)[gi - 256] = z;
        }
        if (gi < (M + 3) / 4) ((float4*)nrm)[gi] = z;

        const int rbase = b * 32;
        const int rows = min(32, M - rbase);
        #pragma unroll
        for (int it = 0; it < 8; ++it) {
            int flat = it * 256 + t;
            int row = flat >> 6;
            int k = (flat & 63) * 4;
            if (row < rows) {
                int grow = rbase + row;
                const float* src = (grow < nsubrow)
                    ? subx + (size_t)grow * 256 + k
                    : x + (size_t)(grow - nsubrow) * 256 + k;
                float4 v = *(const float4*)src;
                unsigned short h0 = f2bf(v.x), h1 = f2bf(v.y), h2 = f2bf(v.z), h3 = f2bf(v.w);
                uint2 hp;
                hp.x = ((unsigned)h1 << 16) | h0;  hp.y = ((unsigned)h3 << 16) | h2;
                int chunk = (row >> 4) * 8 + (k >> 5);
                int lne = (row & 15) | (((k >> 3) & 3) << 4);
                *(uint2*)&sX[chunk * 512 + lne * 8 + (k & 7)] = hp;
            }
        }
        __syncthreads();
        const int cvalid = (rows >> 4) * 8;
        const size_t base = (size_t)rbase * 256;
        #pragma unroll
        for (int it = 0; it < 4; ++it) {
            int flat = it * 256 + t;
            if ((flat >> 6) < cvalid)
                *(bf16x8*)&XF[base + flat * 8] = *(const bf16x8*)&sX[flat * 8];
        }
    } else if (b < nsplitblk + 512) {
        // W1 [256,512] -> [512 rows, 256 k], single bf16 plane
        int idx = (b - nsplitblk) * 256 + t;
        int n = idx >> 8, k = idx & 255;
        float w = W1[(size_t)k * 512 + n];
        int chunk = (n >> 4) * 8 + (k >> 5);
        int lne = (n & 15) | (((k >> 3) & 3) << 4);
        w1h[chunk * 512 + lne * 8 + (k & 7)] = f2bf(w);
    } else {
        // W2 [512,128] -> [128 rows, 512 k], single bf16 plane
        int idx = (b - nsplitblk - 512) * 256 + t;
        int n = idx >> 9, k = idx & 511;
        float w = W2[(size_t)k * 128 + n];
        int chunk = (n >> 4) * 16 + (k >> 5);
        int lne = (n & 15) | (((k >> 3) & 3) << 4);
        w2h[chunk * 512 + lne * 8 + (k & 7)] = f2bf(w);
    }
}

// ---------------------------------------------------------------------------
// Layer-1: z1 = relu(X@W1^T + bias), single-plane bf16 MFMA (unchanged R13).
// Stage-once + barrier-free: 32KB B tile staged once; unrolled 8-iter K-loop
// = 2 coalesced frag A-loads + 4 ds_read_b128 + 8 MFMA per wave, no barriers.
// ---------------------------------------------------------------------------
__global__ __launch_bounds__(256) void gemm_l1(
    const unsigned short* __restrict__ XF,
    const unsigned short* __restrict__ BhF,
    const float* __restrict__ bias, unsigned short* __restrict__ z1F, int M)
{
    __shared__ __align__(16) unsigned short sB[16384];  // 32 chunks; ctile aliases

    const int nb = gridDim.x;
    const int per = nb >> 3, rem = nb & 7;
    const int xcd = blockIdx.x & 7, slot = blockIdx.x >> 3;
    const int newbid = xcd * per + min(xcd, rem) + slot;
    const int m0 = (newbid >> 3) * 128, n0 = (newbid & 7) * 64;

    const int t = threadIdx.x, wave = t >> 6, lane = t & 63;
    const int quad = lane >> 4, lq = lane & 15;
    const int lastch = (M >> 4) - 1;

    #pragma unroll
    for (int q = 0; q < 8; ++q) {
        int c = wave * 8 + q;
        int nc = c >> 3, kc = c & 7;
        const unsigned short* src = BhF
            + ((size_t)((n0 >> 4) + nc)) * 4096 + kc * 512 + lane * 8;
        async16(sB + c * 512, src);
    }

    const unsigned short* pA[2];
    #pragma unroll
    for (int mi = 0; mi < 2; ++mi) {
        int mc = min((m0 >> 4) + wave * 2 + mi, lastch);
        pA[mi] = XF + (size_t)mc * 4096 + lane * 8;
    }

    f32x4 acc[2][4];
    #pragma unroll
    for (int i = 0; i < 2; ++i)
        #pragma unroll
        for (int j = 0; j < 4; ++j) acc[i][j] = (f32x4){0.f, 0.f, 0.f, 0.f};

    __syncthreads();   // single staging drain

    #pragma unroll
    for (int kc = 0; kc < 8; ++kc) {
        bf16x8 fA[2];
        #pragma unroll
        for (int mi = 0; mi < 2; ++mi)
            fA[mi] = *(const bf16x8*)(pA[mi] + kc * 512);
        #pragma unroll
        for (int ni = 0; ni < 4; ++ni) {
            bf16x8 fB = *(const bf16x8*)&sB[(ni * 8 + kc) * 512 + lane * 8];
            #pragma unroll
            for (int mi = 0; mi < 2; ++mi)
                acc[mi][ni] = __builtin_amdgcn_mfma_f32_16x16x32_bf16(fA[mi], fB, acc[mi][ni], 0, 0, 0);
        }
    }

    __syncthreads();
    unsigned short* ctile = sB;
    float bv[4];
    #pragma unroll
    for (int ni = 0; ni < 4; ++ni) bv[ni] = bias[n0 + ni * 16 + lq];
    #pragma unroll
    for (int mi = 0; mi < 2; ++mi)
        #pragma unroll
        for (int ni = 0; ni < 4; ++ni)
            #pragma unroll
            for (int r = 0; r < 4; ++r) {
                float v = fmaxf(acc[mi][ni][r] + bv[ni], 0.f);
                ctile[(wave * 32 + mi * 16 + quad * 4 + r) * 72 + ni * 16 + lq] = f2bf(v);
            }
    __syncthreads();
    #pragma unroll
    for (int it = 0; it < 4; ++it) {
        int flat = it * 256 + t;
        int c = flat >> 6, l = flat & 63;
        int mcl = c >> 1, kc2 = c & 1;
        int gmc = (m0 >> 4) + mcl;
        if (gmc * 16 < M) {
            bf16x8 v = *(const bf16x8*)&ctile[(mcl * 16 + (l & 15)) * 72 + kc2 * 32 + (l >> 4) * 8];
            *(bf16x8*)&z1F[((size_t)gmc * 16 + (n0 >> 5) + kc2) * 512 + l * 8] = v;
        }
    }
}

// ---------------------------------------------------------------------------
// Layer-2: emb = relu(z1@W2^T + bias), SINGLE-plane W2 (lo dropped).
// 256x32 tile, 32KB W2-slice staged once, barrier-free 16-iter K-loop
// (4 A-loads + 2 ds + 8 MFMA per wave-iter). Epilogue: frag-order emb +
// per-row 32-col norm partials via atomicAdd (nrm zeroed in prep).
// ---------------------------------------------------------------------------
__global__ __launch_bounds__(256) void gemm_l2_norm(
    const unsigned short* __restrict__ AF,
    const unsigned short* __restrict__ BhF,
    const float* __restrict__ bias, unsigned short* __restrict__ embF,
    float* __restrict__ nrm, int M)
{
    __shared__ __align__(16) unsigned short sB[18432];  // stage 32KB? no: 32 chunks=16KB + ctile 256x36

    const int nb = gridDim.x;
    const int per = nb >> 3, rem = nb & 7;
    const int xcd = blockIdx.x & 7, slot = blockIdx.x >> 3;
    const int newbid = xcd * per + min(xcd, rem) + slot;
    const int m0 = (newbid >> 2) * 256, n0 = (newbid & 3) * 32;

    const int t = threadIdx.x, wave = t >> 6, lane = t & 63;
    const int quad = lane >> 4, lq = lane & 15;
    const int lastch = (M >> 4) - 1;

    // stage W2 slice once: chunks [nc(2)][kc(16)] = 32 chunks, 8 per wave
    #pragma unroll
    for (int q = 0; q < 8; ++q) {
        int c = wave * 8 + q;
        int nc = c >> 4, kc = c & 15;
        const unsigned short* src = BhF
            + ((size_t)((n0 >> 4) + nc)) * 8192 + kc * 512 + lane * 8;
        async16(sB + c * 512, src);
    }

    const unsigned short* pA[4];
    #pragma unroll
    for (int mi = 0; mi < 4; ++mi) {
        int mc = min((m0 >> 4) + wave * 4 + mi, lastch);
        pA[mi] = AF + (size_t)mc * 8192 + lane * 8;
    }

    f32x4 acc[4][2];
    #pragma unroll
    for (int i = 0; i < 4; ++i)
        #pragma unroll
        for (int j = 0; j < 2; ++j) acc[i][j] = (f32x4){0.f, 0.f, 0.f, 0.f};

    __syncthreads();   // single staging drain

    #pragma unroll 4
    for (int kc = 0; kc < 16; ++kc) {
        bf16x8 fA[4];
        #pragma unroll
        for (int mi = 0; mi < 4; ++mi)
            fA[mi] = *(const bf16x8*)(pA[mi] + kc * 512);
        #pragma unroll
        for (int ni = 0; ni < 2; ++ni) {
            bf16x8 fB = *(const bf16x8*)&sB[(ni * 16 + kc) * 512 + lane * 8];
            #pragma unroll
            for (int mi = 0; mi < 4; ++mi)
                acc[mi][ni] = __builtin_amdgcn_mfma_f32_16x16x32_bf16(fA[mi], fB, acc[mi][ni], 0, 0, 0);
        }
    }

    // epilogue via 256x36 ctile (aliases sB)
    __syncthreads();
    unsigned short* ctile = sB;
    float bv[2];
    #pragma unroll
    for (int ni = 0; ni < 2; ++ni) bv[ni] = bias[n0 + ni * 16 + lq];
    #pragma unroll
    for (int mi = 0; mi < 4; ++mi)
        #pragma unroll
        for (int ni = 0; ni < 2; ++ni)
            #pragma unroll
            for (int r = 0; r < 4; ++r) {
                float v = fmaxf(acc[mi][ni][r] + bv[ni], 0.f);
                ctile[(wave * 64 + mi * 16 + quad * 4 + r) * 36 + ni * 16 + lq] = f2bf(v);
            }
    __syncthreads();

    #pragma unroll
    for (int it = 0; it < 4; ++it) {
        int flat = it * 256 + t;
        int c = flat >> 6, l = flat & 63;
        int gmc = (m0 >> 4) + c;
        if (gmc * 16 < M) {
            bf16x8 v = *(const bf16x8*)&ctile[(c * 16 + (l & 15)) * 36 + (l >> 4) * 8];
            *(bf16x8*)&embF[((size_t)gmc * 4 + (n0 >> 5)) * 512 + l * 8] = v;
        }
    }
    int gm = m0 + t;
    if (gm < M) {
        float s = 0.f;
        #pragma unroll
        for (int seg = 0; seg < 4; ++seg) {
            bf16x8 v = *(const bf16x8*)&ctile[t * 36 + seg * 8];
            #pragma unroll
            for (int e = 0; e < 8; ++e) {
                float f = bf2f((unsigned short)v[e]);
                s = fmaf(f, f, s);
            }
        }
        atomicAdd(&nrm[gm], s);
    }
}

// ---------------------------------------------------------------------------
// Flash NCA (unchanged from R10): frag-order emb + async16 LDS staging.
// ---------------------------------------------------------------------------
__global__ __launch_bounds__(256) void nca_flash_mfma(
    const unsigned short* __restrict__ embF, const float* __restrict__ nrm,
    const float* __restrict__ y, float* __restrict__ gl, float* __restrict__ gy,
    int N, int jspan)
{
    __shared__ __align__(16) unsigned short sB[16384];  // 32 chunks = 128 j-rows
    __shared__ float s2s[128], ys[128];

    const int t = threadIdx.x, wave = t >> 6, lane = t & 63;
    const int quad = lane >> 4, lq = lane & 15;
    const int i0 = blockIdx.x * 64;
    const int j0base = blockIdx.y * jspan;
    const int jend = min(j0base + jspan, N);

    bf16x8 fa[4];
    const int hc = ((N + i0) >> 4) + wave;
    #pragma unroll
    for (int kk = 0; kk < 4; ++kk)
        fa[kk] = *(const bf16x8*)&embF[((size_t)hc * 4 + kk) * 512 + lane * 8];
    float myh2[4];
    #pragma unroll
    for (int r = 0; r < 4; ++r) myh2[r] = nrm[N + i0 + wave * 16 + quad * 4 + r];

    float lacc[4] = {0.f, 0.f, 0.f, 0.f};
    float yacc[4] = {0.f, 0.f, 0.f, 0.f};

    for (int j0 = j0base; j0 < jend; j0 += 128) {
        __syncthreads();
        #pragma unroll
        for (int q = 0; q < 8; ++q) {
            int c = wave * 8 + q;
            async16(sB + c * 512,
                    embF + ((size_t)(j0 >> 4) * 4 + c) * 512 + lane * 8);
        }
        if (t < 128) {
            int j = j0 + t;
            s2s[t] = (j < jend) ? nrm[j] : 1e30f;   // OOB -> p = 0
            ys[t]  = (j < jend) ? y[j] : 0.f;
        }
        __syncthreads();

        f32x4 acc[8];
        #pragma unroll
        for (int jt = 0; jt < 8; ++jt) acc[jt] = (f32x4){0.f, 0.f, 0.f, 0.f};
        #pragma unroll
        for (int kk = 0; kk < 4; ++kk) {
            #pragma unroll
            for (int jt = 0; jt < 8; ++jt) {
                bf16x8 b = *(const bf16x8*)&sB[(jt * 4 + kk) * 512 + lane * 8];
                acc[jt] = __builtin_amdgcn_mfma_f32_16x16x32_bf16(fa[kk], b, acc[jt], 0, 0, 0);
            }
        }

        #pragma unroll
        for (int jt = 0; jt < 8; ++jt) {
            int col = jt * 16 + lq;
            float ss = s2s[col];
            float sy = ys[col];
            #pragma unroll
            for (int r = 0; r < 4; ++r) {
                float d2 = myh2[r] + ss - 2.f * acc[jt][r];
                float d  = sqrtf(fmaxf(d2, 0.f) + EPSF);
                float p  = __expf(-d);
                lacc[r] += p;
                yacc[r]  = fmaf(p, sy, yacc[r]);
            }
        }
    }

    #pragma unroll
    for (int r = 0; r < 4; ++r) {
        #pragma unroll
        for (int off = 8; off > 0; off >>= 1) {
            lacc[r] += __shfl_down(lacc[r], off, 16);
            yacc[r] += __shfl_down(yacc[r], off, 16);
        }
    }
    if (lq == 0) {
        int row = i0 + wave * 16 + quad * 4;
        #pragma unroll
        for (int r = 0; r < 4; ++r) {
            atomicAdd(&gl[row + r], lacc[r]);
            atomicAdd(&gy[row + r], yacc[r]);
        }
    }
}

__global__ __launch_bounds__(256) void finalize_div(
    const float* __restrict__ gl, const float* __restrict__ gy,
    float* __restrict__ out, int B)
{
    int i = blockIdx.x * 256 + threadIdx.x;
    if (i < B) out[i] = gy[i] / gl[i];
}

// ---------------------------------------------------------------------------
extern "C" void kernel_launch(void* const* d_in, const int* in_sizes, int n_in,
                              void* d_out, int out_size, void* d_ws, size_t ws_size,
                              hipStream_t stream)
{
    const float* x    = (const float*)d_in[0];  // [1024,256]
    const float* subx = (const float*)d_in[1];  // [30000,256]
    const float* suby = (const float*)d_in[2];  // [30000]
    const float* W1   = (const float*)d_in[3];  // [256,512]
    const float* b1   = (const float*)d_in[4];  // [512]
    const float* W2   = (const float*)d_in[5];  // [512,128]
    const float* b2   = (const float*)d_in[6];  // [128]
    float* out = (float*)d_out;                 // [1024]

    const int B = 1024, N = 30000, D = 256, H1 = 512, H2 = 128;
    const int M = N + B;  // 31024

    char* wsb = (char*)d_ws;
    size_t off = 0;
    auto alloc = [&](size_t bytes) -> char* {
        char* p = wsb + off;
        off += (bytes + 255) & ~(size_t)255;
        return p;
    };
    unsigned short* cx   = (unsigned short*)alloc((size_t)M * D * 2);
    unsigned short* w1hT = (unsigned short*)alloc((size_t)H1 * D * 2);
    unsigned short* w2hT = (unsigned short*)alloc((size_t)H2 * H1 * 2);
    unsigned short* z1   = (unsigned short*)alloc((size_t)M * H1 * 2);
    unsigned short* emb  = (unsigned short*)alloc((size_t)M * H2 * 2);
    float* nrm = (float*)alloc((size_t)M * 4);
    float* gl  = (float*)alloc((size_t)B * 4);
    float* gy  = (float*)alloc((size_t)B * 4);
    (void)ws_size; (void)in_sizes; (void)n_in; (void)out_size;

    dim3 blk(256);
    // fused prep: split + weight transposes + accumulator zeroing
    const int NSPLITBLK = (M + 31) / 32;                 // 970
    prep<<<dim3(NSPLITBLK + 512 + 256), blk, 0, stream>>>(
        subx, x, W1, W2, cx, w1hT, w2hT, gl, gy, nrm, M, N, NSPLITBLK);
    // layer 1 (single-plane W1): 243 m x 8 n = 1944 blocks
    gemm_l1<<<dim3(((M + 127) / 128) * (H1 / 64)), blk, 0, stream>>>(
        cx, w1hT, b1, z1, M);
    // layer 2 (single-plane W2) + atomic row norms: 122 m x 4 n = 488 blocks
    gemm_l2_norm<<<dim3(((M + 255) / 256) * (H2 / 32)), blk, 0, stream>>>(
        z1, w2hT, b2, emb, nrm, M);
    // pairwise + softmax-weighted sum: 16 i-blocks x 59 j-splits
    const int JSPAN = 512;
    const int NSPLIT = (N + JSPAN - 1) / JSPAN;  // 59
    nca_flash_mfma<<<dim3(B / 64, NSPLIT), blk, 0, stream>>>(
        emb, nrm, suby, gl, gy, N, JSPAN);
    finalize_div<<<dim3(B / 256), blk, 0, stream>>>(gl, gy, out, B);
}